// Round 3
// baseline (543.440 us; speedup 1.0000x reference)
//
#include <hip/hip_runtime.h>
#include <hip/hip_bf16.h>
#include <cstdint>

// Problem constants (fixed by setup_inputs)
constexpr int B    = 4;
constexpr int N    = 784;    // tokens
constexpr int C    = 384;
constexpr int NH   = 8;
constexpr int D    = 48;     // C/NH
constexpr int Himg = 56;
constexpr int Wimg = 56;
constexpr int HW   = 3136;   // Himg*Wimg
constexpr int NSRC = 3136;   // N0
constexpr int NWIN = 64;     // 8x8 windows of 7x7
constexpr int KWIN = 49;     // keys per window
constexpr int C2   = 2 * C;  // 768

// ---- workspace layout (float units unless noted) ----
// zeroed region first (single memset):
constexpr size_t OFF_PW      = 0;                          // B*N*NWIN
constexpr size_t SZ_PW       = (size_t)B * N * NWIN;       // 200704
constexpr size_t OFF_MP      = OFF_PW + SZ_PW;             // B*HW*C
constexpr size_t SZ_MP       = (size_t)B * HW * C;         // 4816896
constexpr size_t OFF_CSUM    = OFF_MP + SZ_MP;             // B*HW
constexpr size_t SZ_CSUM     = (size_t)B * HW;
constexpr size_t OFF_CNT     = OFF_CSUM + SZ_CSUM;         // B*HW
constexpr size_t SZ_CNT      = (size_t)B * HW;
constexpr size_t ZERO_FLOATS = OFF_CNT + SZ_CNT;           // 5,042,688
// non-zeroed:
constexpr size_t OFF_Q       = ZERO_FLOATS;                // B*N*C
constexpr size_t SZ_Q        = (size_t)B * N * C;
constexpr size_t OFF_CONF    = OFF_Q + SZ_Q;               // B*HW
constexpr size_t SZ_CONF     = (size_t)B * HW;
constexpr size_t OFF_IDXW    = OFF_CONF + SZ_CONF;         // B*N ints
constexpr size_t SZ_IDXW     = (size_t)B * N;
constexpr size_t OFF_ATTNO   = OFF_IDXW + SZ_IDXW;         // B*N*C
constexpr size_t SZ_ATTNO    = (size_t)B * N * C;
constexpr size_t OFF_KV_F    = OFF_ATTNO + SZ_ATTNO;       // kv stored as bf16 here
constexpr size_t SZ_KV_BF16  = (size_t)B * HW * C2;        // elements (2 bytes each)
constexpr size_t MAIN_BYTES  = OFF_KV_F * 4 + SZ_KV_BF16 * 2;  // 49,134,848
constexpr size_t OFF_FLAG_BYTE = MAIN_BYTES;               // int flag: 1 = fp32 inputs
constexpr size_t WS_BYTES_NEEDED = MAIN_BYTES + 16;

__device__ __forceinline__ float b2f(__hip_bfloat16 x) { return __bfloat162float(x); }

// Flag-dispatched input load: f32=true -> fp32 buffer, else bf16 buffer.
__device__ __forceinline__ float ldin(const void* p, size_t i, bool f32) {
    if (f32) return ((const float*)p)[i];
    return __bfloat162float(((const __hip_bfloat16*)p)[i]);
}

// grid index per reference _grid_idx (fp32, RNE rounding == jnp.round)
__device__ __forceinline__ void grid_idx(float lx, float ly, int& xg, int& yg) {
    float xf = 0.5f * (lx + 1.0f) * (float)Wimg - 0.5f;
    float yf = 0.5f * (ly + 1.0f) * (float)Himg - 0.5f;
    int x = (int)rintf(xf);
    int y = (int)rintf(yf);
    xg = min(max(x, 0), Wimg - 1);
    yg = min(max(y, 0), Himg - 1);
}

// K0: dtype sniffer. Reads first 512 halfwords of q_w as bf16 and counts
// absurd magnitudes. Genuine bf16 q_w (std 0.02): count == 0. fp32 buffer
// reinterpreted: low halfwords are random mantissa bits -> ~49% have |v|>4.
__global__ __launch_bounds__(64) void sniff_kernel(const unsigned short* __restrict__ qw_bits,
                                                   int* __restrict__ flag) {
    int t = threadIdx.x;
    int cnt = 0;
    #pragma unroll
    for (int i = 0; i < 8; i++) {
        unsigned u = qw_bits[t * 8 + i];
        float v = __uint_as_float(u << 16);
        if (fabsf(v) > 4.0f) cnt++;
    }
    #pragma unroll
    for (int off = 32; off >= 1; off >>= 1) cnt += __shfl_xor(cnt, off);
    if (t == 0) *flag = (cnt > 8) ? 1 : 0;
}

// K1: pw[b, idx_agg[b,p], win(p)] += agg_weight[b,p]
__global__ __launch_bounds__(256) void scatter_pw_kernel(
    const void* __restrict__ loc,      // (B,NSRC,2)
    const int* __restrict__ idx_agg,   // (B,NSRC)
    const void* __restrict__ agg_w,    // (B,NSRC,1)
    float* __restrict__ pw,            // (B,N,NWIN)
    const int* __restrict__ flagp)
{
    const bool f32 = (*flagp != 0);
    int p = blockIdx.x * 256 + threadIdx.x;
    if (p >= B * NSRC) return;
    int b = p / NSRC;
    float lx = ldin(loc, (size_t)p * 2 + 0, f32);
    float ly = ldin(loc, (size_t)p * 2 + 1, f32);
    int xg, yg; grid_idx(lx, ly, xg, yg);
    int win = (yg / 7) * 8 + (xg / 7);
    int n = idx_agg[p];
    float w = ldin(agg_w, p, f32);
    atomicAdd(&pw[((size_t)b * N + n) * NWIN + win], w);
}

// K2: token2map scatter
__global__ __launch_bounds__(128) void scatter_map_kernel(
    const void* __restrict__ loc,          // (B,NSRC,2)
    const int* __restrict__ idx_agg_src,   // (B,NSRC)
    const void* __restrict__ x_source,     // (B,N,C)
    const void* __restrict__ conf_src,     // (B,N,1)
    float* __restrict__ mp, float* __restrict__ csum, float* __restrict__ cnt,
    const int* __restrict__ flagp)
{
    const bool f32 = (*flagp != 0);
    int p = blockIdx.x;               // b*NSRC + p0
    int b = p / NSRC;
    float lx = ldin(loc, (size_t)p * 2 + 0, f32);
    float ly = ldin(loc, (size_t)p * 2 + 1, f32);
    int xg, yg; grid_idx(lx, ly, xg, yg);
    int pix = yg * Wimg + xg;
    int s = idx_agg_src[p];
    size_t srow = ((size_t)b * N + s) * C;
    float* drow = mp + ((size_t)b * HW + pix) * C;
    for (int c = threadIdx.x; c < C; c += 128)
        atomicAdd(&drow[c], ldin(x_source, srow + c, f32));
    if (threadIdx.x == 0) {
        atomicAdd(&csum[(size_t)b * HW + pix], ldin(conf_src, (size_t)b * N + s, f32));
        atomicAdd(&cnt[(size_t)b * HW + pix], 1.0f);
    }
}

// K3: idx_window = argmax(pw, axis=-1), first-max tiebreak
__global__ __launch_bounds__(256) void argmax_kernel(const float* __restrict__ pw, int* __restrict__ idxw)
{
    int t = blockIdx.x * 256 + threadIdx.x;
    if (t >= B * N) return;
    const float* row = pw + (size_t)t * NWIN;
    float best = row[0]; int bi = 0;
    for (int j = 1; j < NWIN; j++) {
        float v = row[j];
        if (v > best) { best = v; bi = j; }
    }
    idxw[t] = bi;
}

// K4: normalize: mp *= 1/(cnt+1e-6) in place; conf = csum/(cnt+1e-6)
__global__ __launch_bounds__(128) void normalize_kernel(
    float* __restrict__ mp, const float* __restrict__ csum,
    const float* __restrict__ cnt, float* __restrict__ conf)
{
    int r = blockIdx.x;  // b*HW + pix
    float inv = 1.0f / (cnt[r] + 1e-6f);
    float* row = mp + (size_t)r * C;
    for (int c = threadIdx.x; c < C; c += 128)
        row[c] *= inv;
    if (threadIdx.x == 0) conf[r] = csum[r] * inv;
}

// Generic tiled GEMM: Co[m,n] = (sum_k A[m,k]*Bw[k,n] + bias[n]) * alpha
// a_mode: 0 = A is fp32 workspace, 2 = A is flag-dtyped input
// c_mode: 0 = store fp32 (ws), 1 = store bf16 (ws kv), 2 = flag-dtyped output
__global__ __launch_bounds__(256) void gemm_bias_kernel(
    const void* __restrict__ A, int a_mode,
    const void* __restrict__ Bw, const void* __restrict__ bias,
    void* __restrict__ Co, int c_mode,
    int M, int Nn, int K, float alpha, const int* __restrict__ flagp)
{
    const bool f32 = (*flagp != 0);
    const bool a_f32 = (a_mode == 0) || f32;
    const bool store_f32 = (c_mode == 0) || (c_mode == 2 && f32);
    constexpr int BM = 64, BN = 64, BK = 16;
    __shared__ float As[BK][BM + 1];
    __shared__ float Bs[BK][BN];
    const int bm = blockIdx.y * BM, bn = blockIdx.x * BN;
    const int t = threadIdx.x;
    const int tm = (t >> 4) << 2;   // (t/16)*4
    const int tn = (t & 15) << 2;   // (t%16)*4
    float acc[4][4] = {};
    for (int k0 = 0; k0 < K; k0 += BK) {
        #pragma unroll
        for (int j = 0; j < 4; j++) {
            int e = t + j * 256;
            int m = e >> 4, kk = e & 15;
            As[kk][m] = ldin(A, (size_t)(bm + m) * K + (k0 + kk), a_f32);
        }
        #pragma unroll
        for (int j = 0; j < 4; j++) {
            int e = t + j * 256;
            int kk = e >> 6, n = e & 63;
            Bs[kk][n] = ldin(Bw, (size_t)(k0 + kk) * Nn + (bn + n), f32);
        }
        __syncthreads();
        #pragma unroll
        for (int kk = 0; kk < BK; kk++) {
            float a[4], bb[4];
            #pragma unroll
            for (int i = 0; i < 4; i++) a[i] = As[kk][tm + i];
            #pragma unroll
            for (int j = 0; j < 4; j++) bb[j] = Bs[kk][tn + j];
            #pragma unroll
            for (int i = 0; i < 4; i++)
                #pragma unroll
                for (int j = 0; j < 4; j++)
                    acc[i][j] += a[i] * bb[j];
        }
        __syncthreads();
    }
    #pragma unroll
    for (int i = 0; i < 4; i++) {
        #pragma unroll
        for (int j = 0; j < 4; j++) {
            float v = (acc[i][j] + ldin(bias, bn + tn + j, f32)) * alpha;
            size_t idx = (size_t)(bm + tm + i) * Nn + (bn + tn + j);
            if (store_f32) ((float*)Co)[idx] = v;
            else           ((__hip_bfloat16*)Co)[idx] = __float2bfloat16(v);
        }
    }
}

// K7: windowed attention, per-thread version. One thread per (b, n, head).
// Two-pass online softmax, all finite arithmetic, register-resident q/acc.
__global__ __launch_bounds__(256) void attn_simple_kernel(
    const float* __restrict__ q,              // (B*N, C) pre-scaled by 1/sqrt(D)
    const __hip_bfloat16* __restrict__ kv,    // (B*HW, 2C): [k(384) | v(384)]
    const float* __restrict__ conf,           // (B*HW)
    const int* __restrict__ idxw,             // (B*N)
    float* __restrict__ attno)                // (B*N, C)
{
    int t = blockIdx.x * 256 + threadIdx.x;
    if (t >= B * N * NH) return;
    int h  = t % NH;
    int bn = t / NH;
    int b  = bn / N;
    int w  = idxw[bn];
    int wy = w >> 3, wx = w & 7;   // nw = 8 windows per row

    float qv[D];
    #pragma unroll
    for (int d = 0; d < D; d++) qv[d] = q[(size_t)bn * C + h * D + d];

    // pass 1: running max m and sum s of exp(logit - m)
    float m = -1e30f, s = 0.0f;
    for (int kk = 0; kk < KWIN; kk++) {
        int pix = (wy * 7 + kk / 7) * Wimg + (wx * 7 + kk % 7);
        const __hip_bfloat16* krow = kv + ((size_t)b * HW + pix) * C2 + h * D;
        float l = conf[(size_t)b * HW + pix];
        #pragma unroll
        for (int d = 0; d < D; d++) l += qv[d] * b2f(krow[d]);
        if (l > m) { s = s * expf(m - l) + 1.0f; m = l; }
        else       { s += expf(l - m); }
    }
    // pass 2: recompute logits, accumulate p * v
    float acc[D];
    #pragma unroll
    for (int d = 0; d < D; d++) acc[d] = 0.0f;
    for (int kk = 0; kk < KWIN; kk++) {
        int pix = (wy * 7 + kk / 7) * Wimg + (wx * 7 + kk % 7);
        const __hip_bfloat16* krow = kv + ((size_t)b * HW + pix) * C2 + h * D;
        const __hip_bfloat16* vrow = krow + C;
        float l = conf[(size_t)b * HW + pix];
        #pragma unroll
        for (int d = 0; d < D; d++) l += qv[d] * b2f(krow[d]);
        float p = expf(l - m) / s;
        #pragma unroll
        for (int d = 0; d < D; d++) acc[d] += p * b2f(vrow[d]);
    }
    #pragma unroll
    for (int d = 0; d < D; d++) attno[(size_t)bn * C + h * D + d] = acc[d];
}

extern "C" void kernel_launch(void* const* d_in, const int* in_sizes, int n_in,
                              void* d_out, int out_size, void* d_ws, size_t ws_size,
                              hipStream_t stream) {
    if (ws_size < WS_BYTES_NEEDED) return;  // visible failure if ws too small

    const void* x        = d_in[0];
    const void* loc      = d_in[1];
    const int*  idx_agg  = (const int*)d_in[2];
    const void* agg_w    = d_in[3];
    const void* x_source = d_in[4];
    const int*  idx_asrc = (const int*)d_in[5];
    const void* conf_src = d_in[6];
    // Weight block normally starts at 9 (d_in[7]=H, d_in[8]=W scalar arrays).
    int wb = 9;
    if (!(n_in >= 15 && in_sizes[7] == 1 && in_sizes[8] == 1)) wb = 7;
    const void* q_w    = d_in[wb + 0];
    const void* q_b    = d_in[wb + 1];
    const void* kv_w   = d_in[wb + 2];
    const void* kv_b   = d_in[wb + 3];
    const void* proj_w = d_in[wb + 4];
    const void* proj_b = d_in[wb + 5];

    float* ws   = (float*)d_ws;
    float* pw   = ws + OFF_PW;
    float* mp   = ws + OFF_MP;
    float* csum = ws + OFF_CSUM;
    float* cnt  = ws + OFF_CNT;
    float* q    = ws + OFF_Q;
    float* conf = ws + OFF_CONF;
    int*   idxw = (int*)(ws + OFF_IDXW);
    float* attno = ws + OFF_ATTNO;
    __hip_bfloat16* kv = (__hip_bfloat16*)(ws + OFF_KV_F);
    int*   flag = (int*)((char*)d_ws + OFF_FLAG_BYTE);

    // dtype sniff (writes flag; everything below reads it on-device)
    sniff_kernel<<<1, 64, 0, stream>>>((const unsigned short*)q_w, flag);

    // zero accumulators (pw, mp, csum, cnt are contiguous)
    hipMemsetAsync(ws, 0, ZERO_FLOATS * sizeof(float), stream);

    // scatter pw
    scatter_pw_kernel<<<(B * NSRC + 255) / 256, 256, 0, stream>>>(loc, idx_agg, agg_w, pw, flag);
    // token2map scatter
    scatter_map_kernel<<<B * NSRC, 128, 0, stream>>>(loc, idx_asrc, x_source, conf_src, mp, csum, cnt, flag);
    // argmax -> idx_window
    argmax_kernel<<<(B * N + 255) / 256, 256, 0, stream>>>(pw, idxw);
    // normalize map
    normalize_kernel<<<B * HW, 128, 0, stream>>>(mp, csum, cnt, conf);

    // q = (x @ q_w + q_b) * scale    (fold softmax scale)
    const float scale = (float)(1.0 / sqrt((double)D));
    gemm_bias_kernel<<<dim3(C / 64, (B * N) / 64), 256, 0, stream>>>(
        x, 2, q_w, q_b, q, 0, B * N, C, C, scale, flag);
    // kv = xs @ kv_w + kv_b   (bf16 ws output)
    gemm_bias_kernel<<<dim3(C2 / 64, (B * HW) / 64), 256, 0, stream>>>(
        mp, 0, kv_w, kv_b, kv, 1, B * HW, C2, C, 1.0f, flag);
    // attention (per-thread, simple)
    attn_simple_kernel<<<(B * N * NH + 255) / 256, 256, 0, stream>>>(q, kv, conf, idxw, attno);
    // out = attno @ proj_w + proj_b  (flag-dtyped output)
    gemm_bias_kernel<<<dim3(C / 64, (B * N) / 64), 256, 0, stream>>>(
        attno, 0, proj_w, proj_b, d_out, 2, B * N, C, C, 1.0f, flag);

    (void)out_size;
}

// Round 4
// 469.187 us; speedup vs baseline: 1.1583x; 1.1583x over previous
//
#include <hip/hip_runtime.h>
#include <hip/hip_bf16.h>
#include <cstdint>

// Problem constants (fixed by setup_inputs)
constexpr int B    = 4;
constexpr int N    = 784;    // tokens
constexpr int C    = 384;
constexpr int NH   = 8;
constexpr int D    = 48;     // C/NH
constexpr int Himg = 56;
constexpr int Wimg = 56;
constexpr int HW   = 3136;   // Himg*Wimg
constexpr int NSRC = 3136;   // N0
constexpr int NWIN = 64;     // 8x8 windows of 7x7
constexpr int KWIN = 49;     // keys per window
constexpr int C2   = 2 * C;  // 768

// ---- workspace layout (float units unless noted) ----
constexpr size_t OFF_PW      = 0;                          // B*N*NWIN
constexpr size_t SZ_PW       = (size_t)B * N * NWIN;       // 200704
constexpr size_t OFF_MP      = OFF_PW + SZ_PW;             // B*HW*C
constexpr size_t SZ_MP       = (size_t)B * HW * C;         // 4816896
constexpr size_t OFF_CSUM    = OFF_MP + SZ_MP;             // B*HW
constexpr size_t SZ_CSUM     = (size_t)B * HW;
constexpr size_t OFF_CNT     = OFF_CSUM + SZ_CSUM;         // B*HW
constexpr size_t SZ_CNT      = (size_t)B * HW;
constexpr size_t ZERO_FLOATS = OFF_CNT + SZ_CNT;           // 5,042,688
// non-zeroed:
constexpr size_t OFF_Q       = ZERO_FLOATS;                // B*N*C fp32
constexpr size_t SZ_Q        = (size_t)B * N * C;
constexpr size_t OFF_CONF    = OFF_Q + SZ_Q;               // B*HW fp32
constexpr size_t SZ_CONF     = (size_t)B * HW;
constexpr size_t OFF_IDXW    = OFF_CONF + SZ_CONF;         // B*N ints
constexpr size_t SZ_IDXW     = (size_t)B * N;
constexpr size_t OFF_ATTNO   = OFF_IDXW + SZ_IDXW;         // B*N*C fp32
constexpr size_t SZ_ATTNO    = (size_t)B * N * C;
constexpr size_t OFF_KV_F    = OFF_ATTNO + SZ_ATTNO;       // kv bf16
constexpr size_t SZ_KV_BF16  = (size_t)B * HW * C2;        // elements
constexpr size_t MAIN_BYTES  = OFF_KV_F * 4 + SZ_KV_BF16 * 2;  // 49,134,848
// transposed bf16 weights (built per launch):
constexpr size_t OFF_KVWT_BYTE = MAIN_BYTES;               // (768,384) bf16
constexpr size_t SZ_KVWT       = (size_t)C2 * C;
constexpr size_t OFF_QWT_BYTE  = OFF_KVWT_BYTE + SZ_KVWT * 2;  // (384,384) bf16
constexpr size_t SZ_QWT        = (size_t)C * C;
constexpr size_t OFF_FLAG_BYTE = OFF_QWT_BYTE + SZ_QWT * 2;
constexpr size_t WS_BYTES_NEEDED = OFF_FLAG_BYTE + 16;     // ~50.0 MB

typedef __attribute__((ext_vector_type(8))) short bf16x8;          // MFMA A/B frag
typedef __attribute__((ext_vector_type(8))) unsigned short u16x8;  // raw staging
typedef __attribute__((ext_vector_type(4))) float f32x4;           // MFMA C/D frag

__device__ __forceinline__ float b2f(__hip_bfloat16 x) { return __bfloat162float(x); }
__device__ __forceinline__ unsigned short f2bf_bits(float f) {
    __hip_bfloat16 h = __float2bfloat16(f);
    return *reinterpret_cast<unsigned short*>(&h);
}

// Flag-dispatched input load: f32=true -> fp32 buffer, else bf16 buffer.
__device__ __forceinline__ float ldin(const void* p, size_t i, bool f32) {
    if (f32) return ((const float*)p)[i];
    return __bfloat162float(((const __hip_bfloat16*)p)[i]);
}

// grid index per reference _grid_idx (fp32, RNE rounding == jnp.round)
__device__ __forceinline__ void grid_idx(float lx, float ly, int& xg, int& yg) {
    float xf = 0.5f * (lx + 1.0f) * (float)Wimg - 0.5f;
    float yf = 0.5f * (ly + 1.0f) * (float)Himg - 0.5f;
    int x = (int)rintf(xf);
    int y = (int)rintf(yf);
    xg = min(max(x, 0), Wimg - 1);
    yg = min(max(y, 0), Himg - 1);
}

// K0: dtype sniffer (fp32 vs bf16 inputs), see round-2 notes.
__global__ __launch_bounds__(64) void sniff_kernel(const unsigned short* __restrict__ qw_bits,
                                                   int* __restrict__ flag) {
    int t = threadIdx.x;
    int cnt = 0;
    #pragma unroll
    for (int i = 0; i < 8; i++) {
        unsigned u = qw_bits[t * 8 + i];
        float v = __uint_as_float(u << 16);
        if (fabsf(v) > 4.0f) cnt++;
    }
    #pragma unroll
    for (int off = 32; off >= 1; off >>= 1) cnt += __shfl_xor(cnt, off);
    if (t == 0) *flag = (cnt > 8) ? 1 : 0;
}

// K1: pw[b, idx_agg[b,p], win(p)] += agg_weight[b,p]
__global__ __launch_bounds__(256) void scatter_pw_kernel(
    const void* __restrict__ loc, const int* __restrict__ idx_agg,
    const void* __restrict__ agg_w, float* __restrict__ pw,
    const int* __restrict__ flagp)
{
    const bool f32 = (*flagp != 0);
    int p = blockIdx.x * 256 + threadIdx.x;
    if (p >= B * NSRC) return;
    int b = p / NSRC;
    float lx = ldin(loc, (size_t)p * 2 + 0, f32);
    float ly = ldin(loc, (size_t)p * 2 + 1, f32);
    int xg, yg; grid_idx(lx, ly, xg, yg);
    int win = (yg / 7) * 8 + (xg / 7);
    int n = idx_agg[p];
    float w = ldin(agg_w, p, f32);
    atomicAdd(&pw[((size_t)b * N + n) * NWIN + win], w);
}

// K2: token2map scatter
__global__ __launch_bounds__(128) void scatter_map_kernel(
    const void* __restrict__ loc, const int* __restrict__ idx_agg_src,
    const void* __restrict__ x_source, const void* __restrict__ conf_src,
    float* __restrict__ mp, float* __restrict__ csum, float* __restrict__ cnt,
    const int* __restrict__ flagp)
{
    const bool f32 = (*flagp != 0);
    int p = blockIdx.x;
    int b = p / NSRC;
    float lx = ldin(loc, (size_t)p * 2 + 0, f32);
    float ly = ldin(loc, (size_t)p * 2 + 1, f32);
    int xg, yg; grid_idx(lx, ly, xg, yg);
    int pix = yg * Wimg + xg;
    int s = idx_agg_src[p];
    size_t srow = ((size_t)b * N + s) * C;
    float* drow = mp + ((size_t)b * HW + pix) * C;
    for (int c = threadIdx.x; c < C; c += 128)
        atomicAdd(&drow[c], ldin(x_source, srow + c, f32));
    if (threadIdx.x == 0) {
        atomicAdd(&csum[(size_t)b * HW + pix], ldin(conf_src, (size_t)b * N + s, f32));
        atomicAdd(&cnt[(size_t)b * HW + pix], 1.0f);
    }
}

// K3: idx_window = argmax(pw, axis=-1), first-max tiebreak
__global__ __launch_bounds__(256) void argmax_kernel(const float* __restrict__ pw, int* __restrict__ idxw)
{
    int t = blockIdx.x * 256 + threadIdx.x;
    if (t >= B * N) return;
    const float* row = pw + (size_t)t * NWIN;
    float best = row[0]; int bi = 0;
    for (int j = 1; j < NWIN; j++) {
        float v = row[j];
        if (v > best) { best = v; bi = j; }
    }
    idxw[t] = bi;
}

// K4: normalize: mp *= 1/(cnt+1e-6) in place; conf = csum/(cnt+1e-6)
__global__ __launch_bounds__(128) void normalize_kernel(
    float* __restrict__ mp, const float* __restrict__ csum,
    const float* __restrict__ cnt, float* __restrict__ conf)
{
    int r = blockIdx.x;
    float inv = 1.0f / (cnt[r] + 1e-6f);
    float* row = mp + (size_t)r * C;
    for (int c = threadIdx.x; c < C; c += 128)
        row[c] *= inv;
    if (threadIdx.x == 0) conf[r] = csum[r] * inv;
}

// K5: transpose + convert weight W (K,Nn) flag-dtype -> Wt (Nn,K) bf16 bits
__global__ __launch_bounds__(256) void transpose_conv_kernel(
    const void* __restrict__ W, unsigned short* __restrict__ Wt,
    int K, int Nn, const int* __restrict__ flagp)
{
    const bool f32 = (*flagp != 0);
    __shared__ float tile[32][33];
    int n0 = blockIdx.x * 32, k0 = blockIdx.y * 32;
    int tx = threadIdx.x & 31, ty = threadIdx.x >> 5;  // 32 x 8
    #pragma unroll
    for (int i = 0; i < 4; i++)
        tile[ty + i * 8][tx] = ldin(W, (size_t)(k0 + ty + i * 8) * Nn + (n0 + tx), f32);
    __syncthreads();
    #pragma unroll
    for (int i = 0; i < 4; i++)
        Wt[(size_t)(n0 + ty + i * 8) * K + (k0 + tx)] = f2bf_bits(tile[tx][ty + i * 8]);
}

// K6: MFMA GEMM. Co[m,n] = (sum_k A[m,k]*B[k,n] + bias[n]) * alpha
// A: (M,K), a_mode 0 = fp32 ws, 2 = flag-dtyped input. Converted to bf16 in staging.
// Bt: (Nn,K) bf16-bits (pre-transposed weights).
// c_mode: 0 = fp32 store, 1 = bf16 store.
// Tile 128x128, BK=32, 4 waves each owning a 64x64 quadrant (4x4 MFMA 16x16x32).
// M may be non-multiple of 128 (clamped loads, guarded stores); Nn multiple of 128.
__global__ __launch_bounds__(256) void mfma_gemm_kernel(
    const void* __restrict__ A, int a_mode,
    const unsigned short* __restrict__ Bt,
    const void* __restrict__ bias,
    void* __restrict__ Co, int c_mode,
    int M, int Nn, int K, float alpha, const int* __restrict__ flagp)
{
    const bool f32 = (*flagp != 0);
    const bool a_f32 = (a_mode == 0) ? true : f32;
    __shared__ unsigned short As[128 * 32];
    __shared__ unsigned short Bs[128 * 32];
    const int t = threadIdx.x;
    const int wave = t >> 6, lane = t & 63;
    const int quad = lane >> 4, l16 = lane & 15;
    const int wm = (wave >> 1) * 64, wn = (wave & 1) * 64;
    const int bm = blockIdx.y * 128, bn = blockIdx.x * 128;

    f32x4 acc[4][4] = {};

    for (int k0 = 0; k0 < K; k0 += 32) {
        // stage A (128 rows x 32 cols) and Bt slab (128 n-rows x 32 k-cols)
        #pragma unroll
        for (int ss = 0; ss < 2; ss++) {
            int s = t + ss * 256;          // 0..511 chunk slots
            int row = s >> 2, ch = s & 3;
            // A: convert to bf16 in registers
            int grow = bm + row; if (grow >= M) grow = M - 1;
            size_t ga = (size_t)grow * K + k0 + ch * 8;
            u16x8 av;
            #pragma unroll
            for (int j = 0; j < 8; j++) av[j] = f2bf_bits(ldin(A, ga + j, a_f32));
            *(u16x8*)&As[row * 32 + ch * 8] = av;
            // B: already bf16 bits
            *(u16x8*)&Bs[row * 32 + ch * 8] =
                *(const u16x8*)(Bt + (size_t)(bn + row) * K + k0 + ch * 8);
        }
        __syncthreads();

        bf16x8 af[4], bf[4];
        #pragma unroll
        for (int i = 0; i < 4; i++) {
            af[i] = *(const bf16x8*)&As[(wm + i * 16 + l16) * 32 + quad * 8];
            bf[i] = *(const bf16x8*)&Bs[(wn + i * 16 + l16) * 32 + quad * 8];
        }
        #pragma unroll
        for (int i = 0; i < 4; i++)
            #pragma unroll
            for (int j = 0; j < 4; j++)
                acc[i][j] = __builtin_amdgcn_mfma_f32_16x16x32_bf16(af[i], bf[j], acc[i][j], 0, 0, 0);
        __syncthreads();
    }

    // epilogue: C/D layout col=lane&15, row=quad*4+reg
    #pragma unroll
    for (int i = 0; i < 4; i++) {
        int growb = bm + wm + i * 16 + quad * 4;
        #pragma unroll
        for (int j = 0; j < 4; j++) {
            int gcol = bn + wn + j * 16 + l16;
            float bv = ldin(bias, gcol, f32);
            #pragma unroll
            for (int r = 0; r < 4; r++) {
                int grow = growb + r;
                if (grow < M) {
                    float v = (acc[i][j][r] + bv) * alpha;
                    size_t idx = (size_t)grow * Nn + gcol;
                    if (c_mode == 0) ((float*)Co)[idx] = v;
                    else             ((unsigned short*)Co)[idx] = f2bf_bits(v);
                }
            }
        }
    }
}

// K8 (proj stays fp32-VALU this round): Co = (A @ Bw + bias) * alpha
__global__ __launch_bounds__(256) void gemm_bias_kernel(
    const void* __restrict__ A, int a_mode,
    const void* __restrict__ Bw, const void* __restrict__ bias,
    void* __restrict__ Co, int c_mode,
    int M, int Nn, int K, float alpha, const int* __restrict__ flagp)
{
    const bool f32 = (*flagp != 0);
    const bool a_f32 = (a_mode == 0) || f32;
    const bool store_f32 = (c_mode == 0) || (c_mode == 2 && f32);
    constexpr int BM = 64, BN = 64, BK = 16;
    __shared__ float As[BK][BM + 1];
    __shared__ float Bs[BK][BN];
    const int bm = blockIdx.y * BM, bn = blockIdx.x * BN;
    const int t = threadIdx.x;
    const int tm = (t >> 4) << 2;
    const int tn = (t & 15) << 2;
    float acc[4][4] = {};
    for (int k0 = 0; k0 < K; k0 += BK) {
        #pragma unroll
        for (int j = 0; j < 4; j++) {
            int e = t + j * 256;
            int m = e >> 4, kk = e & 15;
            As[kk][m] = ldin(A, (size_t)(bm + m) * K + (k0 + kk), a_f32);
        }
        #pragma unroll
        for (int j = 0; j < 4; j++) {
            int e = t + j * 256;
            int kk = e >> 6, n = e & 63;
            Bs[kk][n] = ldin(Bw, (size_t)(k0 + kk) * Nn + (bn + n), f32);
        }
        __syncthreads();
        #pragma unroll
        for (int kk = 0; kk < BK; kk++) {
            float a[4], bb[4];
            #pragma unroll
            for (int i = 0; i < 4; i++) a[i] = As[kk][tm + i];
            #pragma unroll
            for (int j = 0; j < 4; j++) bb[j] = Bs[kk][tn + j];
            #pragma unroll
            for (int i = 0; i < 4; i++)
                #pragma unroll
                for (int j = 0; j < 4; j++)
                    acc[i][j] += a[i] * bb[j];
        }
        __syncthreads();
    }
    #pragma unroll
    for (int i = 0; i < 4; i++) {
        #pragma unroll
        for (int j = 0; j < 4; j++) {
            float v = (acc[i][j] + ldin(bias, bn + tn + j, f32)) * alpha;
            size_t idx = (size_t)(bm + tm + i) * Nn + (bn + tn + j);
            if (store_f32) ((float*)Co)[idx] = v;
            else           ((__hip_bfloat16*)Co)[idx] = __float2bfloat16(v);
        }
    }
}

// K7: windowed attention, per-thread. One thread per (b, n, head).
__global__ __launch_bounds__(256) void attn_simple_kernel(
    const float* __restrict__ q,
    const __hip_bfloat16* __restrict__ kv,    // (B*HW, 2C): [k | v]
    const float* __restrict__ conf,
    const int* __restrict__ idxw,
    float* __restrict__ attno)
{
    int t = blockIdx.x * 256 + threadIdx.x;
    if (t >= B * N * NH) return;
    int h  = t % NH;
    int bn = t / NH;
    int b  = bn / N;
    int w  = idxw[bn];
    int wy = w >> 3, wx = w & 7;

    float qv[D];
    #pragma unroll
    for (int d = 0; d < D; d++) qv[d] = q[(size_t)bn * C + h * D + d];

    float m = -1e30f, s = 0.0f;
    for (int kk = 0; kk < KWIN; kk++) {
        int pix = (wy * 7 + kk / 7) * Wimg + (wx * 7 + kk % 7);
        const __hip_bfloat16* krow = kv + ((size_t)b * HW + pix) * C2 + h * D;
        float l = conf[(size_t)b * HW + pix];
        #pragma unroll
        for (int d = 0; d < D; d++) l += qv[d] * b2f(krow[d]);
        if (l > m) { s = s * expf(m - l) + 1.0f; m = l; }
        else       { s += expf(l - m); }
    }
    float acc[D];
    #pragma unroll
    for (int d = 0; d < D; d++) acc[d] = 0.0f;
    for (int kk = 0; kk < KWIN; kk++) {
        int pix = (wy * 7 + kk / 7) * Wimg + (wx * 7 + kk % 7);
        const __hip_bfloat16* krow = kv + ((size_t)b * HW + pix) * C2 + h * D;
        const __hip_bfloat16* vrow = krow + C;
        float l = conf[(size_t)b * HW + pix];
        #pragma unroll
        for (int d = 0; d < D; d++) l += qv[d] * b2f(krow[d]);
        float p = expf(l - m) / s;
        #pragma unroll
        for (int d = 0; d < D; d++) acc[d] += p * b2f(vrow[d]);
    }
    #pragma unroll
    for (int d = 0; d < D; d++) attno[(size_t)bn * C + h * D + d] = acc[d];
}

extern "C" void kernel_launch(void* const* d_in, const int* in_sizes, int n_in,
                              void* d_out, int out_size, void* d_ws, size_t ws_size,
                              hipStream_t stream) {
    if (ws_size < WS_BYTES_NEEDED) return;  // visible failure if ws too small

    const void* x        = d_in[0];
    const void* loc      = d_in[1];
    const int*  idx_agg  = (const int*)d_in[2];
    const void* agg_w    = d_in[3];
    const void* x_source = d_in[4];
    const int*  idx_asrc = (const int*)d_in[5];
    const void* conf_src = d_in[6];
    int wb = 9;
    if (!(n_in >= 15 && in_sizes[7] == 1 && in_sizes[8] == 1)) wb = 7;
    const void* q_w    = d_in[wb + 0];
    const void* q_b    = d_in[wb + 1];
    const void* kv_w   = d_in[wb + 2];
    const void* kv_b   = d_in[wb + 3];
    const void* proj_w = d_in[wb + 4];
    const void* proj_b = d_in[wb + 5];

    float* ws   = (float*)d_ws;
    float* pw   = ws + OFF_PW;
    float* mp   = ws + OFF_MP;
    float* csum = ws + OFF_CSUM;
    float* cnt  = ws + OFF_CNT;
    float* q    = ws + OFF_Q;
    float* conf = ws + OFF_CONF;
    int*   idxw = (int*)(ws + OFF_IDXW);
    float* attno = ws + OFF_ATTNO;
    __hip_bfloat16* kv = (__hip_bfloat16*)(ws + OFF_KV_F);
    unsigned short* kvwt = (unsigned short*)((char*)d_ws + OFF_KVWT_BYTE);
    unsigned short* qwt  = (unsigned short*)((char*)d_ws + OFF_QWT_BYTE);
    int* flag = (int*)((char*)d_ws + OFF_FLAG_BYTE);

    // dtype sniff
    sniff_kernel<<<1, 64, 0, stream>>>((const unsigned short*)q_w, flag);
    // zero accumulators
    hipMemsetAsync(ws, 0, ZERO_FLOATS * sizeof(float), stream);
    // pre-transpose weights to (N,K) bf16 for MFMA B-operand
    transpose_conv_kernel<<<dim3(C2 / 32, C / 32), 256, 0, stream>>>(kv_w, kvwt, C, C2, flag);
    transpose_conv_kernel<<<dim3(C / 32, C / 32), 256, 0, stream>>>(q_w, qwt, C, C, flag);

    scatter_pw_kernel<<<(B * NSRC + 255) / 256, 256, 0, stream>>>(loc, idx_agg, agg_w, pw, flag);
    scatter_map_kernel<<<B * NSRC, 128, 0, stream>>>(loc, idx_asrc, x_source, conf_src, mp, csum, cnt, flag);
    argmax_kernel<<<(B * N + 255) / 256, 256, 0, stream>>>(pw, idxw);
    normalize_kernel<<<B * HW, 128, 0, stream>>>(mp, csum, cnt, conf);

    const float scale = (float)(1.0 / sqrt((double)D));
    // q = (x @ q_w + q_b) * scale   [MFMA, fp32 out]
    mfma_gemm_kernel<<<dim3(C / 128, (B * N + 127) / 128), 256, 0, stream>>>(
        x, 2, qwt, q_b, q, 0, B * N, C, C, scale, flag);
    // kv = mp @ kv_w + kv_b         [MFMA, bf16 out]
    mfma_gemm_kernel<<<dim3(C2 / 128, (B * HW) / 128), 256, 0, stream>>>(
        mp, 0, kvwt, kv_b, kv, 1, B * HW, C2, C, 1.0f, flag);
    // attention
    attn_simple_kernel<<<(B * N * NH + 255) / 256, 256, 0, stream>>>(q, kv, conf, idxw, attno);
    // out = attno @ proj_w + proj_b [fp32-VALU, flag-dtyped out]
    gemm_bias_kernel<<<dim3(C / 64, (B * N) / 64), 256, 0, stream>>>(
        attno, 0, proj_w, proj_b, d_out, 2, B * N, C, C, 1.0f, flag);

    (void)out_size;
}

// Round 5
// 389.688 us; speedup vs baseline: 1.3946x; 1.2040x over previous
//
#include <hip/hip_runtime.h>
#include <hip/hip_bf16.h>
#include <cstdint>

// Problem constants (fixed by setup_inputs)
constexpr int B    = 4;
constexpr int N    = 784;    // tokens
constexpr int C    = 384;
constexpr int NH   = 8;
constexpr int D    = 48;     // C/NH
constexpr int Himg = 56;
constexpr int Wimg = 56;
constexpr int HW   = 3136;   // Himg*Wimg
constexpr int NSRC = 3136;   // N0
constexpr int NWIN = 64;     // 8x8 windows of 7x7
constexpr int KWIN = 49;     // keys per window
constexpr int C2   = 2 * C;  // 768

// ---- workspace layout (float units unless noted) ----
constexpr size_t OFF_PW      = 0;                          // B*N*NWIN
constexpr size_t SZ_PW       = (size_t)B * N * NWIN;
constexpr size_t OFF_MP      = OFF_PW + SZ_PW;             // B*HW*C
constexpr size_t SZ_MP       = (size_t)B * HW * C;
constexpr size_t OFF_CSUM    = OFF_MP + SZ_MP;             // B*HW
constexpr size_t SZ_CSUM     = (size_t)B * HW;
constexpr size_t OFF_CNT     = OFF_CSUM + SZ_CSUM;         // B*HW
constexpr size_t SZ_CNT      = (size_t)B * HW;
constexpr size_t ZERO_FLOATS = OFF_CNT + SZ_CNT;           // 5,042,688
// non-zeroed:
constexpr size_t OFF_Q       = ZERO_FLOATS;                // B*N*C fp32
constexpr size_t SZ_Q        = (size_t)B * N * C;
constexpr size_t OFF_CONF    = OFF_Q + SZ_Q;               // B*HW fp32
constexpr size_t SZ_CONF     = (size_t)B * HW;
constexpr size_t OFF_IDXW    = OFF_CONF + SZ_CONF;         // B*N ints
constexpr size_t SZ_IDXW     = (size_t)B * N;
constexpr size_t OFF_ATTNO   = OFF_IDXW + SZ_IDXW;         // B*N*C fp32
constexpr size_t SZ_ATTNO    = (size_t)B * N * C;
constexpr size_t OFF_KV_F    = OFF_ATTNO + SZ_ATTNO;       // kv bf16
constexpr size_t SZ_KV_BF16  = (size_t)B * HW * C2;
constexpr size_t MAIN_BYTES  = OFF_KV_F * 4 + SZ_KV_BF16 * 2;  // 49,134,848
// transposed bf16 weights (built per launch):
constexpr size_t OFF_KVWT_BYTE  = MAIN_BYTES;                      // (768,384) bf16
constexpr size_t SZ_KVWT        = (size_t)C2 * C;
constexpr size_t OFF_QWT_BYTE   = OFF_KVWT_BYTE + SZ_KVWT * 2;     // (384,384) bf16
constexpr size_t SZ_QWT         = (size_t)C * C;
constexpr size_t OFF_PROJWT_BYTE= OFF_QWT_BYTE + SZ_QWT * 2;       // (384,384) bf16
constexpr size_t SZ_PROJWT      = (size_t)C * C;
constexpr size_t OFF_FLAG_BYTE  = OFF_PROJWT_BYTE + SZ_PROJWT * 2;
constexpr size_t WS_BYTES_NEEDED = OFF_FLAG_BYTE + 16;     // ~50.4 MB

typedef __attribute__((ext_vector_type(8))) short bf16x8;          // MFMA A/B frag
typedef __attribute__((ext_vector_type(8))) unsigned short u16x8;  // raw staging
typedef __attribute__((ext_vector_type(4))) float f32x4;           // MFMA C/D frag

__device__ __forceinline__ float b2f(__hip_bfloat16 x) { return __bfloat162float(x); }
__device__ __forceinline__ unsigned short f2bf_bits(float f) {
    __hip_bfloat16 h = __float2bfloat16(f);
    return *reinterpret_cast<unsigned short*>(&h);
}
__device__ __forceinline__ float bfbits2f(unsigned short u) {
    return __uint_as_float(((unsigned)u) << 16);
}

// Flag-dispatched input load: f32=true -> fp32 buffer, else bf16 buffer.
__device__ __forceinline__ float ldin(const void* p, size_t i, bool f32) {
    if (f32) return ((const float*)p)[i];
    return __bfloat162float(((const __hip_bfloat16*)p)[i]);
}

// grid index per reference _grid_idx (fp32, RNE rounding == jnp.round)
__device__ __forceinline__ void grid_idx(float lx, float ly, int& xg, int& yg) {
    float xf = 0.5f * (lx + 1.0f) * (float)Wimg - 0.5f;
    float yf = 0.5f * (ly + 1.0f) * (float)Himg - 0.5f;
    int x = (int)rintf(xf);
    int y = (int)rintf(yf);
    xg = min(max(x, 0), Wimg - 1);
    yg = min(max(y, 0), Himg - 1);
}

// K0: dtype sniffer (fp32 vs bf16 inputs).
__global__ __launch_bounds__(64) void sniff_kernel(const unsigned short* __restrict__ qw_bits,
                                                   int* __restrict__ flag) {
    int t = threadIdx.x;
    int cnt = 0;
    #pragma unroll
    for (int i = 0; i < 8; i++) {
        unsigned u = qw_bits[t * 8 + i];
        float v = __uint_as_float(u << 16);
        if (fabsf(v) > 4.0f) cnt++;
    }
    #pragma unroll
    for (int off = 32; off >= 1; off >>= 1) cnt += __shfl_xor(cnt, off);
    if (t == 0) *flag = (cnt > 8) ? 1 : 0;
}

// K1: pw[b, idx_agg[b,p], win(p)] += agg_weight[b,p]
__global__ __launch_bounds__(256) void scatter_pw_kernel(
    const void* __restrict__ loc, const int* __restrict__ idx_agg,
    const void* __restrict__ agg_w, float* __restrict__ pw,
    const int* __restrict__ flagp)
{
    const bool f32 = (*flagp != 0);
    int p = blockIdx.x * 256 + threadIdx.x;
    if (p >= B * NSRC) return;
    int b = p / NSRC;
    float lx = ldin(loc, (size_t)p * 2 + 0, f32);
    float ly = ldin(loc, (size_t)p * 2 + 1, f32);
    int xg, yg; grid_idx(lx, ly, xg, yg);
    int win = (yg / 7) * 8 + (xg / 7);
    int n = idx_agg[p];
    float w = ldin(agg_w, p, f32);
    atomicAdd(&pw[((size_t)b * N + n) * NWIN + win], w);
}

// K2: token2map scatter
__global__ __launch_bounds__(128) void scatter_map_kernel(
    const void* __restrict__ loc, const int* __restrict__ idx_agg_src,
    const void* __restrict__ x_source, const void* __restrict__ conf_src,
    float* __restrict__ mp, float* __restrict__ csum, float* __restrict__ cnt,
    const int* __restrict__ flagp)
{
    const bool f32 = (*flagp != 0);
    int p = blockIdx.x;
    int b = p / NSRC;
    float lx = ldin(loc, (size_t)p * 2 + 0, f32);
    float ly = ldin(loc, (size_t)p * 2 + 1, f32);
    int xg, yg; grid_idx(lx, ly, xg, yg);
    int pix = yg * Wimg + xg;
    int s = idx_agg_src[p];
    size_t srow = ((size_t)b * N + s) * C;
    float* drow = mp + ((size_t)b * HW + pix) * C;
    for (int c = threadIdx.x; c < C; c += 128)
        atomicAdd(&drow[c], ldin(x_source, srow + c, f32));
    if (threadIdx.x == 0) {
        atomicAdd(&csum[(size_t)b * HW + pix], ldin(conf_src, (size_t)b * N + s, f32));
        atomicAdd(&cnt[(size_t)b * HW + pix], 1.0f);
    }
}

// K3: idx_window = argmax(pw, axis=-1), first-max tiebreak
__global__ __launch_bounds__(256) void argmax_kernel(const float* __restrict__ pw, int* __restrict__ idxw)
{
    int t = blockIdx.x * 256 + threadIdx.x;
    if (t >= B * N) return;
    const float* row = pw + (size_t)t * NWIN;
    float best = row[0]; int bi = 0;
    for (int j = 1; j < NWIN; j++) {
        float v = row[j];
        if (v > best) { best = v; bi = j; }
    }
    idxw[t] = bi;
}

// K4: normalize: mp *= 1/(cnt+1e-6) in place; conf = csum/(cnt+1e-6)
__global__ __launch_bounds__(128) void normalize_kernel(
    float* __restrict__ mp, const float* __restrict__ csum,
    const float* __restrict__ cnt, float* __restrict__ conf)
{
    int r = blockIdx.x;
    float inv = 1.0f / (cnt[r] + 1e-6f);
    float* row = mp + (size_t)r * C;
    for (int c = threadIdx.x; c < C; c += 128)
        row[c] *= inv;
    if (threadIdx.x == 0) conf[r] = csum[r] * inv;
}

// K5: transpose + convert weight W (K,Nn) flag-dtype -> Wt (Nn,K) bf16 bits
__global__ __launch_bounds__(256) void transpose_conv_kernel(
    const void* __restrict__ W, unsigned short* __restrict__ Wt,
    int K, int Nn, const int* __restrict__ flagp)
{
    const bool f32 = (*flagp != 0);
    __shared__ float tile[32][33];
    int n0 = blockIdx.x * 32, k0 = blockIdx.y * 32;
    int tx = threadIdx.x & 31, ty = threadIdx.x >> 5;  // 32 x 8
    #pragma unroll
    for (int i = 0; i < 4; i++)
        tile[ty + i * 8][tx] = ldin(W, (size_t)(k0 + ty + i * 8) * Nn + (n0 + tx), f32);
    __syncthreads();
    #pragma unroll
    for (int i = 0; i < 4; i++)
        Wt[(size_t)(n0 + ty + i * 8) * K + (k0 + tx)] = f2bf_bits(tile[tx][ty + i * 8]);
}

// K6: MFMA GEMM. Co[m,n] = (sum_k A[m,k]*B[k,n] + bias[n]) * alpha
// A: (M,K), a_mode 0 = fp32 ws, 2 = flag-dtyped input. Converted to bf16 in staging.
// Bt: (Nn,K) bf16-bits. c_mode: 0 = fp32, 1 = bf16, 2 = flag-dtyped.
// Tile 128x128, BK=32, 4 waves each owning a 64x64 quadrant (4x4 MFMA 16x16x32).
__global__ __launch_bounds__(256) void mfma_gemm_kernel(
    const void* __restrict__ A, int a_mode,
    const unsigned short* __restrict__ Bt,
    const void* __restrict__ bias,
    void* __restrict__ Co, int c_mode,
    int M, int Nn, int K, float alpha, const int* __restrict__ flagp)
{
    const bool f32 = (*flagp != 0);
    const bool a_f32 = (a_mode == 0) ? true : f32;
    const bool store_f32 = (c_mode == 0) || (c_mode == 2 && f32);
    __shared__ unsigned short As[128 * 32];
    __shared__ unsigned short Bs[128 * 32];
    const int t = threadIdx.x;
    const int wave = t >> 6, lane = t & 63;
    const int quad = lane >> 4, l16 = lane & 15;
    const int wm = (wave >> 1) * 64, wn = (wave & 1) * 64;
    const int bm = blockIdx.y * 128, bn = blockIdx.x * 128;

    f32x4 acc[4][4] = {};

    for (int k0 = 0; k0 < K; k0 += 32) {
        #pragma unroll
        for (int ss = 0; ss < 2; ss++) {
            int s = t + ss * 256;
            int row = s >> 2, ch = s & 3;
            int grow = bm + row; if (grow >= M) grow = M - 1;
            size_t ga = (size_t)grow * K + k0 + ch * 8;
            u16x8 av;
            #pragma unroll
            for (int j = 0; j < 8; j++) av[j] = f2bf_bits(ldin(A, ga + j, a_f32));
            *(u16x8*)&As[row * 32 + ch * 8] = av;
            *(u16x8*)&Bs[row * 32 + ch * 8] =
                *(const u16x8*)(Bt + (size_t)(bn + row) * K + k0 + ch * 8);
        }
        __syncthreads();

        bf16x8 af[4], bf[4];
        #pragma unroll
        for (int i = 0; i < 4; i++) {
            af[i] = *(const bf16x8*)&As[(wm + i * 16 + l16) * 32 + quad * 8];
            bf[i] = *(const bf16x8*)&Bs[(wn + i * 16 + l16) * 32 + quad * 8];
        }
        #pragma unroll
        for (int i = 0; i < 4; i++)
            #pragma unroll
            for (int j = 0; j < 4; j++)
                acc[i][j] = __builtin_amdgcn_mfma_f32_16x16x32_bf16(af[i], bf[j], acc[i][j], 0, 0, 0);
        __syncthreads();
    }

    // epilogue: C/D layout col=lane&15, row=quad*4+reg
    #pragma unroll
    for (int i = 0; i < 4; i++) {
        int growb = bm + wm + i * 16 + quad * 4;
        #pragma unroll
        for (int j = 0; j < 4; j++) {
            int gcol = bn + wn + j * 16 + l16;
            float bv = ldin(bias, gcol, f32);
            #pragma unroll
            for (int r = 0; r < 4; r++) {
                int grow = growb + r;
                if (grow < M) {
                    float v = (acc[i][j][r] + bv) * alpha;
                    size_t idx = (size_t)grow * Nn + gcol;
                    if (store_f32) ((float*)Co)[idx] = v;
                    else             ((unsigned short*)Co)[idx] = f2bf_bits(v);
                }
            }
        }
    }
}

// K7: window-centric attention. One block per (b, window); 8 waves, wave h = head h.
// Window's 49 kv rows staged in LDS once; member tokens found by scanning idxw.
__global__ __launch_bounds__(512) void attn_win_kernel(
    const float* __restrict__ q,              // (B*N, C) pre-scaled
    const __hip_bfloat16* __restrict__ kv,    // (B*HW, 768 halfwords): [k | v]
    const float* __restrict__ conf,           // (B*HW)
    const int* __restrict__ idxw,             // (B*N)
    float* __restrict__ attno)                // (B*N, C)
{
    constexpr int SKV = 770;  // halfword stride; word-stride 385 -> bank stride 1 (<=2-way, free)
    __shared__ unsigned short s_kv[KWIN * SKV];
    __shared__ float s_q[C];
    __shared__ float s_p[NH][KWIN];
    __shared__ float s_conf[KWIN];
    __shared__ int   s_list[N];
    __shared__ int   s_cnt;

    const int t = threadIdx.x;
    const int blk = blockIdx.x;      // b*NWIN + win
    const int b = blk >> 6, win = blk & 63;
    const int wy = win >> 3, wx = win & 7;

    if (t == 0) s_cnt = 0;
    __syncthreads();
    // gather member tokens (order-independent work)
    for (int n = t; n < N; n += 512) {
        if (idxw[b * N + n] == win) {
            int slot = atomicAdd(&s_cnt, 1);
            s_list[slot] = n;
        }
    }
    // stage kv window (49 rows x 768 halfwords = 384 uints/row)
    const unsigned* kvw = (const unsigned*)kv;
    for (int ch = t; ch < KWIN * 384; ch += 512) {
        int row = ch / 384, cw = ch % 384;
        int pix = (wy * 7 + row / 7) * Wimg + wx * 7 + row % 7;
        unsigned val = kvw[((size_t)b * HW + pix) * 384 + cw];
        *(unsigned*)&s_kv[row * SKV + cw * 2] = val;
    }
    if (t < KWIN) {
        int pix = (wy * 7 + t / 7) * Wimg + wx * 7 + t % 7;
        s_conf[t] = conf[(size_t)b * HW + pix];
    }
    __syncthreads();

    const int cnt  = s_cnt;
    const int h    = t >> 6;
    const int lane = t & 63;

    for (int ti = 0; ti < cnt; ti++) {
        const int n = s_list[ti];
        const size_t bn = (size_t)b * N + n;
        if (t < C) s_q[t] = q[bn * C + t];
        __syncthreads();   // s_q visible (also protects vs next overwrite via loop-end barrier)

        // logits: lane = key index (49 active)
        float l = -INFINITY;
        if (lane < KWIN) {
            const unsigned short* krow = &s_kv[lane * SKV + h * D];
            float acc = s_conf[lane];
            #pragma unroll
            for (int d2 = 0; d2 < D / 2; d2++) {
                unsigned w = *(const unsigned*)&krow[d2 * 2];
                float k0 = __uint_as_float((w & 0xffffu) << 16);
                float k1 = __uint_as_float(w & 0xffff0000u);
                acc += s_q[h * D + d2 * 2] * k0 + s_q[h * D + d2 * 2 + 1] * k1;
            }
            l = acc;
        }
        // wave softmax over 64 lanes (inactive lanes contribute -inf / 0)
        float m = l;
        #pragma unroll
        for (int off = 32; off >= 1; off >>= 1) m = fmaxf(m, __shfl_xor(m, off));
        float e = (lane < KWIN) ? expf(l - m) : 0.0f;
        float ssum = e;
        #pragma unroll
        for (int off = 32; off >= 1; off >>= 1) ssum += __shfl_xor(ssum, off);
        if (lane < KWIN) s_p[h][lane] = e / ssum;
        __syncthreads();

        // PV: lane = d (48 active); v at halfword col 384 + h*D + d
        if (lane < D) {
            float acc = 0.0f;
            #pragma unroll 7
            for (int kk = 0; kk < KWIN; kk++) {
                float vv = bfbits2f(s_kv[kk * SKV + C + h * D + lane]);
                acc += s_p[h][kk] * vv;
            }
            attno[bn * C + h * D + lane] = acc;
        }
        __syncthreads();   // all reads of s_q / s_p done before next token overwrites
    }
}

extern "C" void kernel_launch(void* const* d_in, const int* in_sizes, int n_in,
                              void* d_out, int out_size, void* d_ws, size_t ws_size,
                              hipStream_t stream) {
    if (ws_size < WS_BYTES_NEEDED) return;  // visible failure if ws too small

    const void* x        = d_in[0];
    const void* loc      = d_in[1];
    const int*  idx_agg  = (const int*)d_in[2];
    const void* agg_w    = d_in[3];
    const void* x_source = d_in[4];
    const int*  idx_asrc = (const int*)d_in[5];
    const void* conf_src = d_in[6];
    int wb = 9;
    if (!(n_in >= 15 && in_sizes[7] == 1 && in_sizes[8] == 1)) wb = 7;
    const void* q_w    = d_in[wb + 0];
    const void* q_b    = d_in[wb + 1];
    const void* kv_w   = d_in[wb + 2];
    const void* kv_b   = d_in[wb + 3];
    const void* proj_w = d_in[wb + 4];
    const void* proj_b = d_in[wb + 5];

    float* ws   = (float*)d_ws;
    float* pw   = ws + OFF_PW;
    float* mp   = ws + OFF_MP;
    float* csum = ws + OFF_CSUM;
    float* cnt  = ws + OFF_CNT;
    float* q    = ws + OFF_Q;
    float* conf = ws + OFF_CONF;
    int*   idxw = (int*)(ws + OFF_IDXW);
    float* attno = ws + OFF_ATTNO;
    __hip_bfloat16* kv = (__hip_bfloat16*)(ws + OFF_KV_F);
    unsigned short* kvwt   = (unsigned short*)((char*)d_ws + OFF_KVWT_BYTE);
    unsigned short* qwt    = (unsigned short*)((char*)d_ws + OFF_QWT_BYTE);
    unsigned short* projwt = (unsigned short*)((char*)d_ws + OFF_PROJWT_BYTE);
    int* flag = (int*)((char*)d_ws + OFF_FLAG_BYTE);

    // dtype sniff
    sniff_kernel<<<1, 64, 0, stream>>>((const unsigned short*)q_w, flag);
    // zero accumulators
    hipMemsetAsync(ws, 0, ZERO_FLOATS * sizeof(float), stream);
    // pre-transpose weights to (N,K) bf16 for MFMA B-operand
    transpose_conv_kernel<<<dim3(C2 / 32, C / 32), 256, 0, stream>>>(kv_w, kvwt, C, C2, flag);
    transpose_conv_kernel<<<dim3(C / 32, C / 32), 256, 0, stream>>>(q_w, qwt, C, C, flag);
    transpose_conv_kernel<<<dim3(C / 32, C / 32), 256, 0, stream>>>(proj_w, projwt, C, C, flag);

    scatter_pw_kernel<<<(B * NSRC + 255) / 256, 256, 0, stream>>>(loc, idx_agg, agg_w, pw, flag);
    scatter_map_kernel<<<B * NSRC, 128, 0, stream>>>(loc, idx_asrc, x_source, conf_src, mp, csum, cnt, flag);
    argmax_kernel<<<(B * N + 255) / 256, 256, 0, stream>>>(pw, idxw);
    normalize_kernel<<<B * HW, 128, 0, stream>>>(mp, csum, cnt, conf);

    const float scale = (float)(1.0 / sqrt((double)D));
    // q = (x @ q_w + q_b) * scale   [MFMA, fp32 out]
    mfma_gemm_kernel<<<dim3(C / 128, (B * N + 127) / 128), 256, 0, stream>>>(
        x, 2, qwt, q_b, q, 0, B * N, C, C, scale, flag);
    // kv = mp @ kv_w + kv_b         [MFMA, bf16 out]
    mfma_gemm_kernel<<<dim3(C2 / 128, (B * HW) / 128), 256, 0, stream>>>(
        mp, 0, kvwt, kv_b, kv, 1, B * HW, C2, C, 1.0f, flag);
    // attention (window-centric, LDS-staged)
    attn_win_kernel<<<B * NWIN, 512, 0, stream>>>(q, kv, conf, idxw, attno);
    // out = attno @ proj_w + proj_b [MFMA, flag-dtyped out]
    mfma_gemm_kernel<<<dim3(C / 128, (B * N + 127) / 128), 256, 0, stream>>>(
        attno, 0, projwt, proj_b, d_out, 2, B * N, C, C, 1.0f, flag);

    (void)out_size;
}

// Round 6
// 288.553 us; speedup vs baseline: 1.8833x; 1.3505x over previous
//
#include <hip/hip_runtime.h>
#include <hip/hip_bf16.h>
#include <cstdint>
#include <type_traits>

// Problem constants (fixed by setup_inputs)
constexpr int B    = 4;
constexpr int N    = 784;    // tokens
constexpr int C    = 384;
constexpr int NH   = 8;
constexpr int D    = 48;     // C/NH
constexpr int Himg = 56;
constexpr int Wimg = 56;
constexpr int HW   = 3136;   // Himg*Wimg
constexpr int NSRC = 3136;   // N0
constexpr int NWIN = 64;     // 8x8 windows of 7x7
constexpr int KWIN = 49;     // keys per window
constexpr int C2   = 2 * C;  // 768

// ---- workspace layout (float units unless noted) ----
constexpr size_t OFF_PW      = 0;                          // B*N*NWIN
constexpr size_t SZ_PW       = (size_t)B * N * NWIN;
constexpr size_t OFF_MP      = OFF_PW + SZ_PW;             // B*HW*C fp32
constexpr size_t SZ_MP       = (size_t)B * HW * C;
constexpr size_t OFF_CSUM    = OFF_MP + SZ_MP;             // B*HW
constexpr size_t SZ_CSUM     = (size_t)B * HW;
constexpr size_t OFF_CNT     = OFF_CSUM + SZ_CSUM;         // B*HW
constexpr size_t SZ_CNT      = (size_t)B * HW;
constexpr size_t ZERO_FLOATS = OFF_CNT + SZ_CNT;           // 5,042,688
// non-zeroed:
constexpr size_t OFF_Q       = ZERO_FLOATS;                // B*N*C fp32
constexpr size_t SZ_Q        = (size_t)B * N * C;
constexpr size_t OFF_CONF    = OFF_Q + SZ_Q;               // B*HW fp32
constexpr size_t SZ_CONF     = (size_t)B * HW;
constexpr size_t OFF_IDXW    = OFF_CONF + SZ_CONF;         // B*N ints
constexpr size_t SZ_IDXW     = (size_t)B * N;
constexpr size_t OFF_ATTNO   = OFF_IDXW + SZ_IDXW;         // B*N*C, stored as bf16 now
constexpr size_t SZ_ATTNO    = (size_t)B * N * C;
constexpr size_t OFF_KV_F    = OFF_ATTNO + SZ_ATTNO;       // kv bf16
constexpr size_t SZ_KV_BF16  = (size_t)B * HW * C2;
constexpr size_t MAIN_BYTES  = OFF_KV_F * 4 + SZ_KV_BF16 * 2;  // 49,134,848
// bf16 side buffers (built per launch):
constexpr size_t OFF_KVWT_BYTE  = MAIN_BYTES;                      // (768,384) bf16
constexpr size_t SZ_KVWT        = (size_t)C2 * C;
constexpr size_t OFF_QWT_BYTE   = OFF_KVWT_BYTE + SZ_KVWT * 2;     // (384,384) bf16
constexpr size_t SZ_QWT         = (size_t)C * C;
constexpr size_t OFF_PROJWT_BYTE= OFF_QWT_BYTE + SZ_QWT * 2;       // (384,384) bf16
constexpr size_t SZ_PROJWT      = (size_t)C * C;
constexpr size_t OFF_FLAG_BYTE  = OFF_PROJWT_BYTE + SZ_PROJWT * 2;
constexpr size_t OFF_XBF_BYTE   = OFF_FLAG_BYTE + 16;              // (B*N,C) bf16
constexpr size_t SZ_XBF         = (size_t)B * N * C;
constexpr size_t WS_BYTES_NEEDED = OFF_XBF_BYTE + SZ_XBF * 2;      // ~52.7 MB

typedef __attribute__((ext_vector_type(8))) short bf16x8;          // MFMA A/B frag
typedef __attribute__((ext_vector_type(8))) unsigned short u16x8;  // raw staging
typedef __attribute__((ext_vector_type(4))) float f32x4;           // MFMA C/D frag

__device__ __forceinline__ float b2f(__hip_bfloat16 x) { return __bfloat162float(x); }
__device__ __forceinline__ unsigned short f2bf_bits(float f) {
    __hip_bfloat16 h = __float2bfloat16(f);
    return *reinterpret_cast<unsigned short*>(&h);
}
__device__ __forceinline__ float bfbits2f(unsigned short u) {
    return __uint_as_float(((unsigned)u) << 16);
}

// Flag-dispatched input load: f32=true -> fp32 buffer, else bf16 buffer.
__device__ __forceinline__ float ldin(const void* p, size_t i, bool f32) {
    if (f32) return ((const float*)p)[i];
    return __bfloat162float(((const __hip_bfloat16*)p)[i]);
}

// grid index per reference _grid_idx (fp32, RNE rounding == jnp.round)
__device__ __forceinline__ void grid_idx(float lx, float ly, int& xg, int& yg) {
    float xf = 0.5f * (lx + 1.0f) * (float)Wimg - 0.5f;
    float yf = 0.5f * (ly + 1.0f) * (float)Himg - 0.5f;
    int x = (int)rintf(xf);
    int y = (int)rintf(yf);
    xg = min(max(x, 0), Wimg - 1);
    yg = min(max(y, 0), Himg - 1);
}

// K0: dtype sniffer (fp32 vs bf16 inputs).
__global__ __launch_bounds__(64) void sniff_kernel(const unsigned short* __restrict__ qw_bits,
                                                   int* __restrict__ flag) {
    int t = threadIdx.x;
    int cnt = 0;
    #pragma unroll
    for (int i = 0; i < 8; i++) {
        unsigned u = qw_bits[t * 8 + i];
        float v = __uint_as_float(u << 16);
        if (fabsf(v) > 4.0f) cnt++;
    }
    #pragma unroll
    for (int off = 32; off >= 1; off >>= 1) cnt += __shfl_xor(cnt, off);
    if (t == 0) *flag = (cnt > 8) ? 1 : 0;
}

// K1: pw[b, idx_agg[b,p], win(p)] += agg_weight[b,p]
__global__ __launch_bounds__(256) void scatter_pw_kernel(
    const void* __restrict__ loc, const int* __restrict__ idx_agg,
    const void* __restrict__ agg_w, float* __restrict__ pw,
    const int* __restrict__ flagp)
{
    const bool f32 = (*flagp != 0);
    int p = blockIdx.x * 256 + threadIdx.x;
    if (p >= B * NSRC) return;
    int b = p / NSRC;
    float lx = ldin(loc, (size_t)p * 2 + 0, f32);
    float ly = ldin(loc, (size_t)p * 2 + 1, f32);
    int xg, yg; grid_idx(lx, ly, xg, yg);
    int win = (yg / 7) * 8 + (xg / 7);
    int n = idx_agg[p];
    float w = ldin(agg_w, p, f32);
    atomicAdd(&pw[((size_t)b * N + n) * NWIN + win], w);
}

// K2: token2map scatter
__global__ __launch_bounds__(128) void scatter_map_kernel(
    const void* __restrict__ loc, const int* __restrict__ idx_agg_src,
    const void* __restrict__ x_source, const void* __restrict__ conf_src,
    float* __restrict__ mp, float* __restrict__ csum, float* __restrict__ cnt,
    const int* __restrict__ flagp)
{
    const bool f32 = (*flagp != 0);
    int p = blockIdx.x;
    int b = p / NSRC;
    float lx = ldin(loc, (size_t)p * 2 + 0, f32);
    float ly = ldin(loc, (size_t)p * 2 + 1, f32);
    int xg, yg; grid_idx(lx, ly, xg, yg);
    int pix = yg * Wimg + xg;
    int s = idx_agg_src[p];
    size_t srow = ((size_t)b * N + s) * C;
    float* drow = mp + ((size_t)b * HW + pix) * C;
    for (int c = threadIdx.x; c < C; c += 128)
        atomicAdd(&drow[c], ldin(x_source, srow + c, f32));
    if (threadIdx.x == 0) {
        atomicAdd(&csum[(size_t)b * HW + pix], ldin(conf_src, (size_t)b * N + s, f32));
        atomicAdd(&cnt[(size_t)b * HW + pix], 1.0f);
    }
}

// K3: idx_window = argmax(pw, axis=-1), first-max tiebreak
__global__ __launch_bounds__(256) void argmax_kernel(const float* __restrict__ pw, int* __restrict__ idxw)
{
    int t = blockIdx.x * 256 + threadIdx.x;
    if (t >= B * N) return;
    const float* row = pw + (size_t)t * NWIN;
    float best = row[0]; int bi = 0;
    for (int j = 1; j < NWIN; j++) {
        float v = row[j];
        if (v > best) { best = v; bi = j; }
    }
    idxw[t] = bi;
}

// K4: normalize: mp *= 1/(cnt+1e-6) in place; conf = csum/(cnt+1e-6)
__global__ __launch_bounds__(128) void normalize_kernel(
    float* __restrict__ mp, const float* __restrict__ csum,
    const float* __restrict__ cnt, float* __restrict__ conf)
{
    int r = blockIdx.x;
    float inv = 1.0f / (cnt[r] + 1e-6f);
    float* row = mp + (size_t)r * C;
    for (int c = threadIdx.x; c < C; c += 128)
        row[c] *= inv;
    if (threadIdx.x == 0) conf[r] = csum[r] * inv;
}

// K4b: flag-dtyped -> bf16 bits conversion (x pre-convert for MFMA A)
__global__ __launch_bounds__(256) void conv_bf16_kernel(
    const void* __restrict__ src, unsigned short* __restrict__ dst,
    int n, const int* __restrict__ flagp)
{
    const bool f32 = (*flagp != 0);
    int i = (blockIdx.x * 256 + threadIdx.x) * 4;
    if (i + 3 < n) {
        #pragma unroll
        for (int j = 0; j < 4; j++)
            dst[i + j] = f2bf_bits(ldin(src, i + j, f32));
    }
}

// K5: transpose + convert weight W (K,Nn) flag-dtype -> Wt (Nn,K) bf16 bits
__global__ __launch_bounds__(256) void transpose_conv_kernel(
    const void* __restrict__ W, unsigned short* __restrict__ Wt,
    int K, int Nn, const int* __restrict__ flagp)
{
    const bool f32 = (*flagp != 0);
    __shared__ float tile[32][33];
    int n0 = blockIdx.x * 32, k0 = blockIdx.y * 32;
    int tx = threadIdx.x & 31, ty = threadIdx.x >> 5;  // 32 x 8
    #pragma unroll
    for (int i = 0; i < 4; i++)
        tile[ty + i * 8][tx] = ldin(W, (size_t)(k0 + ty + i * 8) * Nn + (n0 + tx), f32);
    __syncthreads();
    #pragma unroll
    for (int i = 0; i < 4; i++)
        Wt[(size_t)(n0 + ty + i * 8) * K + (k0 + tx)] = f2bf_bits(tile[tx][ty + i * 8]);
}

// K6: MFMA GEMM, compile-time A dtype (float -> convert in staging; ushort -> bf16 direct).
// Bt: (Nn,K) bf16 bits. c_mode: 0 = fp32 store, 1 = bf16 store, 2 = flag-dtyped store.
// Tile 128x128, BK=32, 4 waves each owning a 64x64 quadrant (4x4 MFMA 16x16x32).
// LDS row stride 40 halfwords (80 B): keeps ds_*_b128 16B-aligned and bank
// aliasing at 2-way (free) instead of 8-way at stride 32.
template <typename AT>
__global__ __launch_bounds__(256) void mfma_gemm_kernel(
    const AT* __restrict__ A,
    const unsigned short* __restrict__ Bt,
    const void* __restrict__ bias,
    void* __restrict__ Co, int c_mode,
    int M, int Nn, int K, float alpha, const int* __restrict__ flagp)
{
    constexpr int SA = 40;  // LDS halfword stride per 32-K row
    const bool f32 = (*flagp != 0);
    const bool store_f32 = (c_mode == 0) || (c_mode == 2 && f32);
    __shared__ unsigned short As[128 * SA];
    __shared__ unsigned short Bs[128 * SA];
    const int t = threadIdx.x;
    const int wave = t >> 6, lane = t & 63;
    const int quad = lane >> 4, l16 = lane & 15;
    const int wm = (wave >> 1) * 64, wn = (wave & 1) * 64;
    const int bm = blockIdx.y * 128, bn = blockIdx.x * 128;

    f32x4 acc[4][4] = {};

    for (int k0 = 0; k0 < K; k0 += 32) {
        #pragma unroll
        for (int ss = 0; ss < 2; ss++) {
            int s = t + ss * 256;
            int row = s >> 2, ch = s & 3;
            int grow = bm + row; if (grow >= M) grow = M - 1;
            if constexpr (std::is_same<AT, float>::value) {
                const float* ga = A + (size_t)grow * K + k0 + ch * 8;
                float4 v0 = *(const float4*)ga;
                float4 v1 = *(const float4*)(ga + 4);
                u16x8 av;
                av[0] = f2bf_bits(v0.x); av[1] = f2bf_bits(v0.y);
                av[2] = f2bf_bits(v0.z); av[3] = f2bf_bits(v0.w);
                av[4] = f2bf_bits(v1.x); av[5] = f2bf_bits(v1.y);
                av[6] = f2bf_bits(v1.z); av[7] = f2bf_bits(v1.w);
                *(u16x8*)&As[row * SA + ch * 8] = av;
            } else {
                *(u16x8*)&As[row * SA + ch * 8] =
                    *(const u16x8*)(A + (size_t)grow * K + k0 + ch * 8);
            }
            *(u16x8*)&Bs[row * SA + ch * 8] =
                *(const u16x8*)(Bt + (size_t)(bn + row) * K + k0 + ch * 8);
        }
        __syncthreads();

        bf16x8 af[4], bf[4];
        #pragma unroll
        for (int i = 0; i < 4; i++) {
            af[i] = *(const bf16x8*)&As[(wm + i * 16 + l16) * SA + quad * 8];
            bf[i] = *(const bf16x8*)&Bs[(wn + i * 16 + l16) * SA + quad * 8];
        }
        #pragma unroll
        for (int i = 0; i < 4; i++)
            #pragma unroll
            for (int j = 0; j < 4; j++)
                acc[i][j] = __builtin_amdgcn_mfma_f32_16x16x32_bf16(af[i], bf[j], acc[i][j], 0, 0, 0);
        __syncthreads();
    }

    // epilogue: C/D layout col=lane&15, row=quad*4+reg
    #pragma unroll
    for (int i = 0; i < 4; i++) {
        int growb = bm + wm + i * 16 + quad * 4;
        #pragma unroll
        for (int j = 0; j < 4; j++) {
            int gcol = bn + wn + j * 16 + l16;
            float bv = ldin(bias, gcol, f32);
            #pragma unroll
            for (int r = 0; r < 4; r++) {
                int grow = growb + r;
                if (grow < M) {
                    float v = (acc[i][j][r] + bv) * alpha;
                    size_t idx = (size_t)grow * Nn + gcol;
                    if (store_f32) ((float*)Co)[idx] = v;
                    else           ((unsigned short*)Co)[idx] = f2bf_bits(v);
                }
            }
        }
    }
}

// K7: window-centric attention. One block per (b, window); 8 waves, wave h = head h.
// Window's 49 kv rows staged in LDS once; member tokens found by scanning idxw.
// attno written as bf16 (numerically identical: proj staging re-rounds anyway).
__global__ __launch_bounds__(512) void attn_win_kernel(
    const float* __restrict__ q,              // (B*N, C) pre-scaled
    const __hip_bfloat16* __restrict__ kv,    // (B*HW, 768 halfwords): [k | v]
    const float* __restrict__ conf,           // (B*HW)
    const int* __restrict__ idxw,             // (B*N)
    unsigned short* __restrict__ attno)       // (B*N, C) bf16 bits
{
    constexpr int SKV = 770;  // halfword stride; word-stride 385 -> <=2-way bank aliasing (free)
    __shared__ unsigned short s_kv[KWIN * SKV];
    __shared__ float s_q[C];
    __shared__ float s_p[NH][KWIN];
    __shared__ float s_conf[KWIN];
    __shared__ int   s_list[N];
    __shared__ int   s_cnt;

    const int t = threadIdx.x;
    const int blk = blockIdx.x;      // b*NWIN + win
    const int b = blk >> 6, win = blk & 63;
    const int wy = win >> 3, wx = win & 7;

    if (t == 0) s_cnt = 0;
    __syncthreads();
    for (int n = t; n < N; n += 512) {
        if (idxw[b * N + n] == win) {
            int slot = atomicAdd(&s_cnt, 1);
            s_list[slot] = n;
        }
    }
    const unsigned* kvw = (const unsigned*)kv;
    for (int ch = t; ch < KWIN * 384; ch += 512) {
        int row = ch / 384, cw = ch % 384;
        int pix = (wy * 7 + row / 7) * Wimg + wx * 7 + row % 7;
        unsigned val = kvw[((size_t)b * HW + pix) * 384 + cw];
        *(unsigned*)&s_kv[row * SKV + cw * 2] = val;
    }
    if (t < KWIN) {
        int pix = (wy * 7 + t / 7) * Wimg + wx * 7 + t % 7;
        s_conf[t] = conf[(size_t)b * HW + pix];
    }
    __syncthreads();

    const int cnt  = s_cnt;
    const int h    = t >> 6;
    const int lane = t & 63;

    for (int ti = 0; ti < cnt; ti++) {
        const int n = s_list[ti];
        const size_t bn = (size_t)b * N + n;
        if (t < C) s_q[t] = q[bn * C + t];
        __syncthreads();

        float l = -INFINITY;
        if (lane < KWIN) {
            const unsigned short* krow = &s_kv[lane * SKV + h * D];
            float acc = s_conf[lane];
            #pragma unroll
            for (int d2 = 0; d2 < D / 2; d2++) {
                unsigned w = *(const unsigned*)&krow[d2 * 2];
                float k0 = __uint_as_float((w & 0xffffu) << 16);
                float k1 = __uint_as_float(w & 0xffff0000u);
                acc += s_q[h * D + d2 * 2] * k0 + s_q[h * D + d2 * 2 + 1] * k1;
            }
            l = acc;
        }
        float m = l;
        #pragma unroll
        for (int off = 32; off >= 1; off >>= 1) m = fmaxf(m, __shfl_xor(m, off));
        float e = (lane < KWIN) ? expf(l - m) : 0.0f;
        float ssum = e;
        #pragma unroll
        for (int off = 32; off >= 1; off >>= 1) ssum += __shfl_xor(ssum, off);
        if (lane < KWIN) s_p[h][lane] = e / ssum;
        __syncthreads();

        if (lane < D) {
            float acc = 0.0f;
            #pragma unroll 7
            for (int kk = 0; kk < KWIN; kk++) {
                float vv = bfbits2f(s_kv[kk * SKV + C + h * D + lane]);
                acc += s_p[h][kk] * vv;
            }
            attno[bn * C + h * D + lane] = f2bf_bits(acc);
        }
        __syncthreads();
    }
}

extern "C" void kernel_launch(void* const* d_in, const int* in_sizes, int n_in,
                              void* d_out, int out_size, void* d_ws, size_t ws_size,
                              hipStream_t stream) {
    if (ws_size < WS_BYTES_NEEDED) return;  // visible failure if ws too small

    const void* x        = d_in[0];
    const void* loc      = d_in[1];
    const int*  idx_agg  = (const int*)d_in[2];
    const void* agg_w    = d_in[3];
    const void* x_source = d_in[4];
    const int*  idx_asrc = (const int*)d_in[5];
    const void* conf_src = d_in[6];
    int wb = 9;
    if (!(n_in >= 15 && in_sizes[7] == 1 && in_sizes[8] == 1)) wb = 7;
    const void* q_w    = d_in[wb + 0];
    const void* q_b    = d_in[wb + 1];
    const void* kv_w   = d_in[wb + 2];
    const void* kv_b   = d_in[wb + 3];
    const void* proj_w = d_in[wb + 4];
    const void* proj_b = d_in[wb + 5];

    float* ws   = (float*)d_ws;
    float* pw   = ws + OFF_PW;
    float* mp   = ws + OFF_MP;
    float* csum = ws + OFF_CSUM;
    float* cnt  = ws + OFF_CNT;
    float* q    = ws + OFF_Q;
    float* conf = ws + OFF_CONF;
    int*   idxw = (int*)(ws + OFF_IDXW);
    unsigned short* attno = (unsigned short*)(ws + OFF_ATTNO);
    __hip_bfloat16* kv = (__hip_bfloat16*)(ws + OFF_KV_F);
    unsigned short* kvwt   = (unsigned short*)((char*)d_ws + OFF_KVWT_BYTE);
    unsigned short* qwt    = (unsigned short*)((char*)d_ws + OFF_QWT_BYTE);
    unsigned short* projwt = (unsigned short*)((char*)d_ws + OFF_PROJWT_BYTE);
    int* flag = (int*)((char*)d_ws + OFF_FLAG_BYTE);
    unsigned short* xbf = (unsigned short*)((char*)d_ws + OFF_XBF_BYTE);

    // dtype sniff
    sniff_kernel<<<1, 64, 0, stream>>>((const unsigned short*)q_w, flag);
    // zero accumulators
    hipMemsetAsync(ws, 0, ZERO_FLOATS * sizeof(float), stream);
    // pre-transpose weights to (N,K) bf16 for MFMA B-operand
    transpose_conv_kernel<<<dim3(C2 / 32, C / 32), 256, 0, stream>>>(kv_w, kvwt, C, C2, flag);
    transpose_conv_kernel<<<dim3(C / 32, C / 32), 256, 0, stream>>>(q_w, qwt, C, C, flag);
    transpose_conv_kernel<<<dim3(C / 32, C / 32), 256, 0, stream>>>(proj_w, projwt, C, C, flag);
    // pre-convert x to bf16 for MFMA A-operand
    conv_bf16_kernel<<<(B * N * C / 4 + 255) / 256, 256, 0, stream>>>(x, xbf, B * N * C, flag);

    scatter_pw_kernel<<<(B * NSRC + 255) / 256, 256, 0, stream>>>(loc, idx_agg, agg_w, pw, flag);
    scatter_map_kernel<<<B * NSRC, 128, 0, stream>>>(loc, idx_asrc, x_source, conf_src, mp, csum, cnt, flag);
    argmax_kernel<<<(B * N + 255) / 256, 256, 0, stream>>>(pw, idxw);
    normalize_kernel<<<B * HW, 128, 0, stream>>>(mp, csum, cnt, conf);

    const float scale = (float)(1.0 / sqrt((double)D));
    // q = (x @ q_w + q_b) * scale   [MFMA, bf16 A, fp32 out]
    mfma_gemm_kernel<unsigned short><<<dim3(C / 128, (B * N + 127) / 128), 256, 0, stream>>>(
        xbf, qwt, q_b, q, 0, B * N, C, C, scale, flag);
    // kv = mp @ kv_w + kv_b         [MFMA, fp32 A vectorized, bf16 out]
    mfma_gemm_kernel<float><<<dim3(C2 / 128, (B * HW) / 128), 256, 0, stream>>>(
        mp, kvwt, kv_b, kv, 1, B * HW, C2, C, 1.0f, flag);
    // attention (window-centric, LDS-staged, bf16 out)
    attn_win_kernel<<<B * NWIN, 512, 0, stream>>>(q, kv, conf, idxw, attno);
    // out = attno @ proj_w + proj_b [MFMA, bf16 A, flag-dtyped out]
    mfma_gemm_kernel<unsigned short><<<dim3(C / 128, (B * N + 127) / 128), 256, 0, stream>>>(
        attno, projwt, proj_b, d_out, 2, B * N, C, C, 1.0f, flag);

    (void)out_size;
}

// Round 7
// 281.981 us; speedup vs baseline: 1.9272x; 1.0233x over previous
//
#include <hip/hip_runtime.h>
#include <hip/hip_bf16.h>
#include <cstdint>
#include <type_traits>

// Problem constants (fixed by setup_inputs)
constexpr int B    = 4;
constexpr int N    = 784;    // tokens
constexpr int C    = 384;
constexpr int NH   = 8;
constexpr int D    = 48;     // C/NH
constexpr int Himg = 56;
constexpr int Wimg = 56;
constexpr int HW   = 3136;   // Himg*Wimg
constexpr int NSRC = 3136;   // N0
constexpr int NWIN = 64;     // 8x8 windows of 7x7
constexpr int KWIN = 49;     // keys per window
constexpr int C2   = 2 * C;  // 768

// ---- workspace layout (float units unless noted) ----
constexpr size_t OFF_PW      = 0;                          // B*N*NWIN
constexpr size_t SZ_PW       = (size_t)B * N * NWIN;
constexpr size_t OFF_MP      = OFF_PW + SZ_PW;             // B*HW*C fp32
constexpr size_t SZ_MP       = (size_t)B * HW * C;
constexpr size_t OFF_CSUM    = OFF_MP + SZ_MP;             // B*HW
constexpr size_t SZ_CSUM     = (size_t)B * HW;
constexpr size_t OFF_CNT     = OFF_CSUM + SZ_CSUM;         // B*HW
constexpr size_t SZ_CNT      = (size_t)B * HW;
constexpr size_t ZERO_FLOATS = OFF_CNT + SZ_CNT;           // 5,042,688
// non-zeroed:
constexpr size_t OFF_Q       = ZERO_FLOATS;                // B*N*C fp32
constexpr size_t SZ_Q        = (size_t)B * N * C;
constexpr size_t OFF_CONF    = OFF_Q + SZ_Q;               // B*HW fp32
constexpr size_t SZ_CONF     = (size_t)B * HW;
constexpr size_t OFF_IDXW    = OFF_CONF + SZ_CONF;         // B*N ints
constexpr size_t SZ_IDXW     = (size_t)B * N;
constexpr size_t OFF_ATTNO   = OFF_IDXW + SZ_IDXW;         // B*N*C, stored as bf16
constexpr size_t SZ_ATTNO    = (size_t)B * N * C;
constexpr size_t OFF_KV_F    = OFF_ATTNO + SZ_ATTNO;       // kv bf16
constexpr size_t SZ_KV_BF16  = (size_t)B * HW * C2;
constexpr size_t MAIN_BYTES  = OFF_KV_F * 4 + SZ_KV_BF16 * 2;  // 49,134,848
// bf16 side buffers (built per launch):
constexpr size_t OFF_KVWT_BYTE  = MAIN_BYTES;                      // (768,384) bf16
constexpr size_t SZ_KVWT        = (size_t)C2 * C;
constexpr size_t OFF_QWT_BYTE   = OFF_KVWT_BYTE + SZ_KVWT * 2;     // (384,384) bf16
constexpr size_t SZ_QWT         = (size_t)C * C;
constexpr size_t OFF_PROJWT_BYTE= OFF_QWT_BYTE + SZ_QWT * 2;       // (384,384) bf16
constexpr size_t SZ_PROJWT      = (size_t)C * C;
constexpr size_t OFF_FLAG_BYTE  = OFF_PROJWT_BYTE + SZ_PROJWT * 2;
constexpr size_t OFF_XBF_BYTE   = OFF_FLAG_BYTE + 16;              // (B*N,C) bf16
constexpr size_t SZ_XBF         = (size_t)B * N * C;
constexpr size_t WS_BYTES_NEEDED = OFF_XBF_BYTE + SZ_XBF * 2;      // ~52.7 MB

typedef __attribute__((ext_vector_type(8))) short bf16x8;          // MFMA A/B frag
typedef __attribute__((ext_vector_type(8))) unsigned short u16x8;  // raw staging
typedef __attribute__((ext_vector_type(4))) float f32x4;           // MFMA C/D frag

__device__ __forceinline__ float b2f(__hip_bfloat16 x) { return __bfloat162float(x); }
__device__ __forceinline__ unsigned short f2bf_bits(float f) {
    __hip_bfloat16 h = __float2bfloat16(f);
    return *reinterpret_cast<unsigned short*>(&h);
}
__device__ __forceinline__ float bfbits2f(unsigned short u) {
    return __uint_as_float(((unsigned)u) << 16);
}

// Flag-dispatched input load: f32=true -> fp32 buffer, else bf16 buffer.
__device__ __forceinline__ float ldin(const void* p, size_t i, bool f32) {
    if (f32) return ((const float*)p)[i];
    return __bfloat162float(((const __hip_bfloat16*)p)[i]);
}

// grid index per reference _grid_idx (fp32, RNE rounding == jnp.round)
__device__ __forceinline__ void grid_idx(float lx, float ly, int& xg, int& yg) {
    float xf = 0.5f * (lx + 1.0f) * (float)Wimg - 0.5f;
    float yf = 0.5f * (ly + 1.0f) * (float)Himg - 0.5f;
    int x = (int)rintf(xf);
    int y = (int)rintf(yf);
    xg = min(max(x, 0), Wimg - 1);
    yg = min(max(y, 0), Himg - 1);
}

// K0: dtype sniffer (fp32 vs bf16 inputs).
__global__ __launch_bounds__(64) void sniff_kernel(const unsigned short* __restrict__ qw_bits,
                                                   int* __restrict__ flag) {
    int t = threadIdx.x;
    int cnt = 0;
    #pragma unroll
    for (int i = 0; i < 8; i++) {
        unsigned u = qw_bits[t * 8 + i];
        float v = __uint_as_float(u << 16);
        if (fabsf(v) > 4.0f) cnt++;
    }
    #pragma unroll
    for (int off = 32; off >= 1; off >>= 1) cnt += __shfl_xor(cnt, off);
    if (t == 0) *flag = (cnt > 8) ? 1 : 0;
}

// K1: pw[b, idx_agg[b,p], win(p)] += agg_weight[b,p]
__global__ __launch_bounds__(256) void scatter_pw_kernel(
    const void* __restrict__ loc, const int* __restrict__ idx_agg,
    const void* __restrict__ agg_w, float* __restrict__ pw,
    const int* __restrict__ flagp)
{
    const bool f32 = (*flagp != 0);
    int p = blockIdx.x * 256 + threadIdx.x;
    if (p >= B * NSRC) return;
    int b = p / NSRC;
    float lx = ldin(loc, (size_t)p * 2 + 0, f32);
    float ly = ldin(loc, (size_t)p * 2 + 1, f32);
    int xg, yg; grid_idx(lx, ly, xg, yg);
    int win = (yg / 7) * 8 + (xg / 7);
    int n = idx_agg[p];
    float w = ldin(agg_w, p, f32);
    atomicAdd(&pw[((size_t)b * N + n) * NWIN + win], w);
}

// K2: token2map scatter
__global__ __launch_bounds__(128) void scatter_map_kernel(
    const void* __restrict__ loc, const int* __restrict__ idx_agg_src,
    const void* __restrict__ x_source, const void* __restrict__ conf_src,
    float* __restrict__ mp, float* __restrict__ csum, float* __restrict__ cnt,
    const int* __restrict__ flagp)
{
    const bool f32 = (*flagp != 0);
    int p = blockIdx.x;
    int b = p / NSRC;
    float lx = ldin(loc, (size_t)p * 2 + 0, f32);
    float ly = ldin(loc, (size_t)p * 2 + 1, f32);
    int xg, yg; grid_idx(lx, ly, xg, yg);
    int pix = yg * Wimg + xg;
    int s = idx_agg_src[p];
    size_t srow = ((size_t)b * N + s) * C;
    float* drow = mp + ((size_t)b * HW + pix) * C;
    for (int c = threadIdx.x; c < C; c += 128)
        atomicAdd(&drow[c], ldin(x_source, srow + c, f32));
    if (threadIdx.x == 0) {
        atomicAdd(&csum[(size_t)b * HW + pix], ldin(conf_src, (size_t)b * N + s, f32));
        atomicAdd(&cnt[(size_t)b * HW + pix], 1.0f);
    }
}

// K3: idx_window = argmax(pw, axis=-1), first-max tiebreak
__global__ __launch_bounds__(256) void argmax_kernel(const float* __restrict__ pw, int* __restrict__ idxw)
{
    int t = blockIdx.x * 256 + threadIdx.x;
    if (t >= B * N) return;
    const float* row = pw + (size_t)t * NWIN;
    float best = row[0]; int bi = 0;
    for (int j = 1; j < NWIN; j++) {
        float v = row[j];
        if (v > best) { best = v; bi = j; }
    }
    idxw[t] = bi;
}

// K4: normalize: mp *= 1/(cnt+1e-6) in place; conf = csum/(cnt+1e-6)
__global__ __launch_bounds__(128) void normalize_kernel(
    float* __restrict__ mp, const float* __restrict__ csum,
    const float* __restrict__ cnt, float* __restrict__ conf)
{
    int r = blockIdx.x;
    float inv = 1.0f / (cnt[r] + 1e-6f);
    float* row = mp + (size_t)r * C;
    for (int c = threadIdx.x; c < C; c += 128)
        row[c] *= inv;
    if (threadIdx.x == 0) conf[r] = csum[r] * inv;
}

// K4b: flag-dtyped -> bf16 bits conversion (x pre-convert for MFMA A)
__global__ __launch_bounds__(256) void conv_bf16_kernel(
    const void* __restrict__ src, unsigned short* __restrict__ dst,
    int n, const int* __restrict__ flagp)
{
    const bool f32 = (*flagp != 0);
    int i = (blockIdx.x * 256 + threadIdx.x) * 4;
    if (i + 3 < n) {
        #pragma unroll
        for (int j = 0; j < 4; j++)
            dst[i + j] = f2bf_bits(ldin(src, i + j, f32));
    }
}

// K5: transpose + convert weight W (K,Nn) flag-dtype -> Wt (Nn,K) bf16 bits
__global__ __launch_bounds__(256) void transpose_conv_kernel(
    const void* __restrict__ W, unsigned short* __restrict__ Wt,
    int K, int Nn, const int* __restrict__ flagp)
{
    const bool f32 = (*flagp != 0);
    __shared__ float tile[32][33];
    int n0 = blockIdx.x * 32, k0 = blockIdx.y * 32;
    int tx = threadIdx.x & 31, ty = threadIdx.x >> 5;  // 32 x 8
    #pragma unroll
    for (int i = 0; i < 4; i++)
        tile[ty + i * 8][tx] = ldin(W, (size_t)(k0 + ty + i * 8) * Nn + (n0 + tx), f32);
    __syncthreads();
    #pragma unroll
    for (int i = 0; i < 4; i++)
        Wt[(size_t)(n0 + ty + i * 8) * K + (k0 + tx)] = f2bf_bits(tile[tx][ty + i * 8]);
}

// K6: MFMA GEMM, compile-time A dtype (float -> convert in staging; ushort -> bf16 direct).
// Bt: (Nn,K) bf16 bits. c_mode: 0 = fp32 store, 1 = bf16 store, 2 = flag-dtyped store.
// Tile 128x128, BK=32, 4 waves each owning a 64x64 quadrant (4x4 MFMA 16x16x32).
// LDS row stride 40 halfwords (80 B): 16B-aligned ds_*_b128, 2-way bank aliasing (free).
template <typename AT>
__global__ __launch_bounds__(256) void mfma_gemm_kernel(
    const AT* __restrict__ A,
    const unsigned short* __restrict__ Bt,
    const void* __restrict__ bias,
    void* __restrict__ Co, int c_mode,
    int M, int Nn, int K, float alpha, const int* __restrict__ flagp)
{
    constexpr int SA = 40;  // LDS halfword stride per 32-K row
    const bool f32 = (*flagp != 0);
    const bool store_f32 = (c_mode == 0) || (c_mode == 2 && f32);
    __shared__ unsigned short As[128 * SA];
    __shared__ unsigned short Bs[128 * SA];
    const int t = threadIdx.x;
    const int wave = t >> 6, lane = t & 63;
    const int quad = lane >> 4, l16 = lane & 15;
    const int wm = (wave >> 1) * 64, wn = (wave & 1) * 64;
    const int bm = blockIdx.y * 128, bn = blockIdx.x * 128;

    f32x4 acc[4][4] = {};

    for (int k0 = 0; k0 < K; k0 += 32) {
        #pragma unroll
        for (int ss = 0; ss < 2; ss++) {
            int s = t + ss * 256;
            int row = s >> 2, ch = s & 3;
            int grow = bm + row; if (grow >= M) grow = M - 1;
            if constexpr (std::is_same<AT, float>::value) {
                const float* ga = A + (size_t)grow * K + k0 + ch * 8;
                float4 v0 = *(const float4*)ga;
                float4 v1 = *(const float4*)(ga + 4);
                u16x8 av;
                av[0] = f2bf_bits(v0.x); av[1] = f2bf_bits(v0.y);
                av[2] = f2bf_bits(v0.z); av[3] = f2bf_bits(v0.w);
                av[4] = f2bf_bits(v1.x); av[5] = f2bf_bits(v1.y);
                av[6] = f2bf_bits(v1.z); av[7] = f2bf_bits(v1.w);
                *(u16x8*)&As[row * SA + ch * 8] = av;
            } else {
                *(u16x8*)&As[row * SA + ch * 8] =
                    *(const u16x8*)(A + (size_t)grow * K + k0 + ch * 8);
            }
            *(u16x8*)&Bs[row * SA + ch * 8] =
                *(const u16x8*)(Bt + (size_t)(bn + row) * K + k0 + ch * 8);
        }
        __syncthreads();

        bf16x8 af[4], bf[4];
        #pragma unroll
        for (int i = 0; i < 4; i++) {
            af[i] = *(const bf16x8*)&As[(wm + i * 16 + l16) * SA + quad * 8];
            bf[i] = *(const bf16x8*)&Bs[(wn + i * 16 + l16) * SA + quad * 8];
        }
        #pragma unroll
        for (int i = 0; i < 4; i++)
            #pragma unroll
            for (int j = 0; j < 4; j++)
                acc[i][j] = __builtin_amdgcn_mfma_f32_16x16x32_bf16(af[i], bf[j], acc[i][j], 0, 0, 0);
        __syncthreads();
    }

    // epilogue: C/D layout col=lane&15, row=quad*4+reg
    #pragma unroll
    for (int i = 0; i < 4; i++) {
        int growb = bm + wm + i * 16 + quad * 4;
        #pragma unroll
        for (int j = 0; j < 4; j++) {
            int gcol = bn + wn + j * 16 + l16;
            float bv = ldin(bias, gcol, f32);
            #pragma unroll
            for (int r = 0; r < 4; r++) {
                int grow = growb + r;
                if (grow < M) {
                    float v = (acc[i][j][r] + bv) * alpha;
                    size_t idx = (size_t)grow * Nn + gcol;
                    if (store_f32) ((float*)Co)[idx] = v;
                    else           ((unsigned short*)Co)[idx] = f2bf_bits(v);
                }
            }
        }
    }
}

// K7: window-centric attention, barrier-free token loop.
// One block per (b, window); 1024 threads = 16 waves. wave = (half = w>>3, head = w&7).
// Window kv staged to LDS once; wave (h, half) processes tokens ti = half, half+2, ...
// All per-token communication is intra-wave: q segment in wave-private LDS slot,
// softmax via wave shuffles, p broadcast via __shfl. Zero __syncthreads in the loop.
__global__ __launch_bounds__(1024) void attn_win_kernel(
    const float* __restrict__ q,              // (B*N, C) pre-scaled
    const unsigned short* __restrict__ kv,    // (B*HW, 768 halfwords): [k | v]
    const float* __restrict__ conf,           // (B*HW)
    const int* __restrict__ idxw,             // (B*N)
    unsigned short* __restrict__ attno)       // (B*N, C) bf16 bits
{
    constexpr int SKV = 770;  // halfword stride; word stride 385 (odd) -> 2-way bank aliasing (free)
    __shared__ unsigned short s_kv[KWIN * SKV];     // 75,460 B
    __shared__ unsigned short s_list[N];            //  1,568 B
    __shared__ float s_conf[KWIN];                  //    196 B
    __shared__ float s_qw[16][D];                   //  3,072 B (wave-private slots)
    __shared__ int   s_cnt;

    const int t = threadIdx.x;
    const int b = blockIdx.x >> 6, win = blockIdx.x & 63;
    const int wy = win >> 3, wx = win & 7;

    if (t == 0) s_cnt = 0;
    __syncthreads();
    // member-token compaction (shared list, order irrelevant: both halves see same list)
    for (int n = t; n < N; n += 1024) {
        if (idxw[b * N + n] == win) {
            int slot = atomicAdd(&s_cnt, 1);
            s_list[slot] = (unsigned short)n;
        }
    }
    // stage kv window (49 rows x 384 words), coalesced
    const unsigned* kvw = (const unsigned*)kv;
    for (int ch = t; ch < KWIN * 384; ch += 1024) {
        int row = ch / 384, cw = ch % 384;
        int pix = (wy * 7 + row / 7) * Wimg + wx * 7 + row % 7;
        *(unsigned*)&s_kv[row * SKV + cw * 2] = kvw[((size_t)b * HW + pix) * 384 + cw];
    }
    if (t < KWIN) {
        int pix = (wy * 7 + t / 7) * Wimg + wx * 7 + t % 7;
        s_conf[t] = conf[(size_t)b * HW + pix];
    }
    __syncthreads();

    const int cnt  = s_cnt;
    const int wave = t >> 6;        // 0..15
    const int lane = t & 63;
    const int h    = wave & 7;      // head
    const int half = wave >> 3;     // token parity

    int ti = half;
    float qv = (ti < cnt && lane < D)
        ? q[((size_t)b * N + s_list[ti]) * C + h * D + lane] : 0.0f;

    for (; ti < cnt; ti += 2) {
        // prefetch next token's q segment (independent -> issues before compute)
        float qv_next = (ti + 2 < cnt && lane < D)
            ? q[((size_t)b * N + s_list[ti + 2]) * C + h * D + lane] : 0.0f;
        const size_t bn = (size_t)b * N + s_list[ti];

        if (lane < D) s_qw[wave][lane] = qv;
        __builtin_amdgcn_wave_barrier();

        // logits: lane = key index (49 active); q read is LDS broadcast (free)
        float l = -INFINITY;
        if (lane < KWIN) {
            const unsigned short* krow = &s_kv[lane * SKV + h * D];
            float acc = s_conf[lane];
            #pragma unroll
            for (int d2 = 0; d2 < D / 2; d2++) {
                unsigned w = *(const unsigned*)&krow[d2 * 2];
                float k0 = __uint_as_float((w & 0xffffu) << 16);
                float k1 = __uint_as_float(w & 0xffff0000u);
                float2 qq = *(const float2*)&s_qw[wave][d2 * 2];
                acc += qq.x * k0 + qq.y * k1;
            }
            l = acc;
        }
        // in-wave softmax
        float m = l;
        #pragma unroll
        for (int off = 32; off >= 1; off >>= 1) m = fmaxf(m, __shfl_xor(m, off));
        float e = (lane < KWIN) ? expf(l - m) : 0.0f;
        float ssum = e;
        #pragma unroll
        for (int off = 32; off >= 1; off >>= 1) ssum += __shfl_xor(ssum, off);
        float p = e / ssum;   // p = 0 on lanes >= KWIN

        // PV: all 64 lanes run the shuffle loop (sources 0..48 must be active)
        float acc = 0.0f;
        const int dl = lane & (D - 1 + 16);  // lane if <48, wrapped otherwise (value discarded)
        #pragma unroll 7
        for (int kk = 0; kk < KWIN; kk++) {
            float pk = __shfl(p, kk);
            float vv = bfbits2f(s_kv[kk * SKV + C + h * D + (lane < D ? lane : 0)]);
            acc += pk * vv;
        }
        if (lane < D) attno[bn * C + h * D + lane] = f2bf_bits(acc);
        (void)dl;

        qv = qv_next;
    }
}

extern "C" void kernel_launch(void* const* d_in, const int* in_sizes, int n_in,
                              void* d_out, int out_size, void* d_ws, size_t ws_size,
                              hipStream_t stream) {
    if (ws_size < WS_BYTES_NEEDED) return;  // visible failure if ws too small

    const void* x        = d_in[0];
    const void* loc      = d_in[1];
    const int*  idx_agg  = (const int*)d_in[2];
    const void* agg_w    = d_in[3];
    const void* x_source = d_in[4];
    const int*  idx_asrc = (const int*)d_in[5];
    const void* conf_src = d_in[6];
    int wb = 9;
    if (!(n_in >= 15 && in_sizes[7] == 1 && in_sizes[8] == 1)) wb = 7;
    const void* q_w    = d_in[wb + 0];
    const void* q_b    = d_in[wb + 1];
    const void* kv_w   = d_in[wb + 2];
    const void* kv_b   = d_in[wb + 3];
    const void* proj_w = d_in[wb + 4];
    const void* proj_b = d_in[wb + 5];

    float* ws   = (float*)d_ws;
    float* pw   = ws + OFF_PW;
    float* mp   = ws + OFF_MP;
    float* csum = ws + OFF_CSUM;
    float* cnt  = ws + OFF_CNT;
    float* q    = ws + OFF_Q;
    float* conf = ws + OFF_CONF;
    int*   idxw = (int*)(ws + OFF_IDXW);
    unsigned short* attno = (unsigned short*)(ws + OFF_ATTNO);
    unsigned short* kv = (unsigned short*)(ws + OFF_KV_F);
    unsigned short* kvwt   = (unsigned short*)((char*)d_ws + OFF_KVWT_BYTE);
    unsigned short* qwt    = (unsigned short*)((char*)d_ws + OFF_QWT_BYTE);
    unsigned short* projwt = (unsigned short*)((char*)d_ws + OFF_PROJWT_BYTE);
    int* flag = (int*)((char*)d_ws + OFF_FLAG_BYTE);
    unsigned short* xbf = (unsigned short*)((char*)d_ws + OFF_XBF_BYTE);

    // dtype sniff
    sniff_kernel<<<1, 64, 0, stream>>>((const unsigned short*)q_w, flag);
    // zero accumulators
    hipMemsetAsync(ws, 0, ZERO_FLOATS * sizeof(float), stream);
    // pre-transpose weights to (N,K) bf16 for MFMA B-operand
    transpose_conv_kernel<<<dim3(C2 / 32, C / 32), 256, 0, stream>>>(kv_w, kvwt, C, C2, flag);
    transpose_conv_kernel<<<dim3(C / 32, C / 32), 256, 0, stream>>>(q_w, qwt, C, C, flag);
    transpose_conv_kernel<<<dim3(C / 32, C / 32), 256, 0, stream>>>(proj_w, projwt, C, C, flag);
    // pre-convert x to bf16 for MFMA A-operand
    conv_bf16_kernel<<<(B * N * C / 4 + 255) / 256, 256, 0, stream>>>(x, xbf, B * N * C, flag);

    scatter_pw_kernel<<<(B * NSRC + 255) / 256, 256, 0, stream>>>(loc, idx_agg, agg_w, pw, flag);
    scatter_map_kernel<<<B * NSRC, 128, 0, stream>>>(loc, idx_asrc, x_source, conf_src, mp, csum, cnt, flag);
    argmax_kernel<<<(B * N + 255) / 256, 256, 0, stream>>>(pw, idxw);
    normalize_kernel<<<B * HW, 128, 0, stream>>>(mp, csum, cnt, conf);

    const float scale = (float)(1.0 / sqrt((double)D));
    // q = (x @ q_w + q_b) * scale   [MFMA, bf16 A, fp32 out]
    mfma_gemm_kernel<unsigned short><<<dim3(C / 128, (B * N + 127) / 128), 256, 0, stream>>>(
        xbf, qwt, q_b, q, 0, B * N, C, C, scale, flag);
    // kv = mp @ kv_w + kv_b         [MFMA, fp32 A vectorized, bf16 out]
    mfma_gemm_kernel<float><<<dim3(C2 / 128, (B * HW) / 128), 256, 0, stream>>>(
        mp, kvwt, kv_b, kv, 1, B * HW, C2, C, 1.0f, flag);
    // attention (window-centric, barrier-free token loop)
    attn_win_kernel<<<B * NWIN, 1024, 0, stream>>>(q, kv, conf, idxw, attno);
    // out = attno @ proj_w + proj_b [MFMA, bf16 A, flag-dtyped out]
    mfma_gemm_kernel<unsigned short><<<dim3(C / 128, (B * N + 127) / 128), 256, 0, stream>>>(
        attno, projwt, proj_b, d_out, 2, B * N, C, C, 1.0f, flag);

    (void)out_size;
}

// Round 8
// 255.057 us; speedup vs baseline: 2.1307x; 1.1056x over previous
//
#include <hip/hip_runtime.h>
#include <hip/hip_bf16.h>
#include <cstdint>
#include <type_traits>

// Problem constants (fixed by setup_inputs)
constexpr int B    = 4;
constexpr int N    = 784;    // tokens
constexpr int C    = 384;
constexpr int NH   = 8;
constexpr int D    = 48;     // C/NH
constexpr int Himg = 56;
constexpr int Wimg = 56;
constexpr int HW   = 3136;   // Himg*Wimg
constexpr int NSRC = 3136;   // N0
constexpr int NWIN = 64;     // 8x8 windows of 7x7
constexpr int KWIN = 49;     // keys per window
constexpr int KPAD = 56;     // padded key count (16B-aligned rows, p-pad zeros)
constexpr int C2   = 2 * C;  // 768

// ---- workspace layout (float units unless noted) ----
constexpr size_t OFF_PW      = 0;                          // B*N*NWIN
constexpr size_t SZ_PW       = (size_t)B * N * NWIN;
constexpr size_t OFF_MP      = OFF_PW + SZ_PW;             // B*HW*C fp32
constexpr size_t SZ_MP       = (size_t)B * HW * C;
constexpr size_t OFF_CSUM    = OFF_MP + SZ_MP;             // B*HW
constexpr size_t SZ_CSUM     = (size_t)B * HW;
constexpr size_t OFF_CNT     = OFF_CSUM + SZ_CSUM;         // B*HW
constexpr size_t SZ_CNT      = (size_t)B * HW;
constexpr size_t ZERO_FLOATS = OFF_CNT + SZ_CNT;           // 5,042,688
// non-zeroed:
constexpr size_t OFF_Q       = ZERO_FLOATS;                // B*N*C fp32
constexpr size_t SZ_Q        = (size_t)B * N * C;
constexpr size_t OFF_CONF    = OFF_Q + SZ_Q;               // B*HW fp32
constexpr size_t SZ_CONF     = (size_t)B * HW;
constexpr size_t OFF_IDXW    = OFF_CONF + SZ_CONF;         // B*N ints
constexpr size_t SZ_IDXW     = (size_t)B * N;
constexpr size_t OFF_ATTNO   = OFF_IDXW + SZ_IDXW;         // B*N*C, stored as bf16
constexpr size_t SZ_ATTNO    = (size_t)B * N * C;
constexpr size_t OFF_KV_F    = OFF_ATTNO + SZ_ATTNO;       // kv bf16
constexpr size_t SZ_KV_BF16  = (size_t)B * HW * C2;
constexpr size_t MAIN_BYTES  = OFF_KV_F * 4 + SZ_KV_BF16 * 2;  // 49,134,848
// bf16 side buffers (built per launch):
constexpr size_t OFF_KVWT_BYTE  = MAIN_BYTES;                      // (768,384) bf16
constexpr size_t SZ_KVWT        = (size_t)C2 * C;
constexpr size_t OFF_QWT_BYTE   = OFF_KVWT_BYTE + SZ_KVWT * 2;     // (384,384) bf16
constexpr size_t SZ_QWT         = (size_t)C * C;
constexpr size_t OFF_PROJWT_BYTE= OFF_QWT_BYTE + SZ_QWT * 2;       // (384,384) bf16
constexpr size_t SZ_PROJWT      = (size_t)C * C;
constexpr size_t OFF_FLAG_BYTE  = OFF_PROJWT_BYTE + SZ_PROJWT * 2;
constexpr size_t OFF_XBF_BYTE   = OFF_FLAG_BYTE + 16;              // (B*N,C) bf16
constexpr size_t SZ_XBF         = (size_t)B * N * C;
constexpr size_t WS_BYTES_NEEDED = OFF_XBF_BYTE + SZ_XBF * 2;      // ~52.7 MB

typedef __attribute__((ext_vector_type(8))) short bf16x8;          // MFMA A/B frag
typedef __attribute__((ext_vector_type(8))) unsigned short u16x8;  // raw staging
typedef __attribute__((ext_vector_type(4))) float f32x4;           // MFMA C/D frag

__device__ __forceinline__ float b2f(__hip_bfloat16 x) { return __bfloat162float(x); }
__device__ __forceinline__ unsigned short f2bf_bits(float f) {
    __hip_bfloat16 h = __float2bfloat16(f);
    return *reinterpret_cast<unsigned short*>(&h);
}
__device__ __forceinline__ float bfbits2f(unsigned short u) {
    return __uint_as_float(((unsigned)u) << 16);
}

// Flag-dispatched input load: f32=true -> fp32 buffer, else bf16 buffer.
__device__ __forceinline__ float ldin(const void* p, size_t i, bool f32) {
    if (f32) return ((const float*)p)[i];
    return __bfloat162float(((const __hip_bfloat16*)p)[i]);
}

// grid index per reference _grid_idx (fp32, RNE rounding == jnp.round)
__device__ __forceinline__ void grid_idx(float lx, float ly, int& xg, int& yg) {
    float xf = 0.5f * (lx + 1.0f) * (float)Wimg - 0.5f;
    float yf = 0.5f * (ly + 1.0f) * (float)Himg - 0.5f;
    int x = (int)rintf(xf);
    int y = (int)rintf(yf);
    xg = min(max(x, 0), Wimg - 1);
    yg = min(max(y, 0), Himg - 1);
}

// K0: dtype sniffer (fp32 vs bf16 inputs).
__global__ __launch_bounds__(64) void sniff_kernel(const unsigned short* __restrict__ qw_bits,
                                                   int* __restrict__ flag) {
    int t = threadIdx.x;
    int cnt = 0;
    #pragma unroll
    for (int i = 0; i < 8; i++) {
        unsigned u = qw_bits[t * 8 + i];
        float v = __uint_as_float(u << 16);
        if (fabsf(v) > 4.0f) cnt++;
    }
    #pragma unroll
    for (int off = 32; off >= 1; off >>= 1) cnt += __shfl_xor(cnt, off);
    if (t == 0) *flag = (cnt > 8) ? 1 : 0;
}

// K1: pw[b, idx_agg[b,p], win(p)] += agg_weight[b,p]
__global__ __launch_bounds__(256) void scatter_pw_kernel(
    const void* __restrict__ loc, const int* __restrict__ idx_agg,
    const void* __restrict__ agg_w, float* __restrict__ pw,
    const int* __restrict__ flagp)
{
    const bool f32 = (*flagp != 0);
    int p = blockIdx.x * 256 + threadIdx.x;
    if (p >= B * NSRC) return;
    int b = p / NSRC;
    float lx = ldin(loc, (size_t)p * 2 + 0, f32);
    float ly = ldin(loc, (size_t)p * 2 + 1, f32);
    int xg, yg; grid_idx(lx, ly, xg, yg);
    int win = (yg / 7) * 8 + (xg / 7);
    int n = idx_agg[p];
    float w = ldin(agg_w, p, f32);
    atomicAdd(&pw[((size_t)b * N + n) * NWIN + win], w);
}

// K2: token2map scatter
__global__ __launch_bounds__(128) void scatter_map_kernel(
    const void* __restrict__ loc, const int* __restrict__ idx_agg_src,
    const void* __restrict__ x_source, const void* __restrict__ conf_src,
    float* __restrict__ mp, float* __restrict__ csum, float* __restrict__ cnt,
    const int* __restrict__ flagp)
{
    const bool f32 = (*flagp != 0);
    int p = blockIdx.x;
    int b = p / NSRC;
    float lx = ldin(loc, (size_t)p * 2 + 0, f32);
    float ly = ldin(loc, (size_t)p * 2 + 1, f32);
    int xg, yg; grid_idx(lx, ly, xg, yg);
    int pix = yg * Wimg + xg;
    int s = idx_agg_src[p];
    size_t srow = ((size_t)b * N + s) * C;
    float* drow = mp + ((size_t)b * HW + pix) * C;
    for (int c = threadIdx.x; c < C; c += 128)
        atomicAdd(&drow[c], ldin(x_source, srow + c, f32));
    if (threadIdx.x == 0) {
        atomicAdd(&csum[(size_t)b * HW + pix], ldin(conf_src, (size_t)b * N + s, f32));
        atomicAdd(&cnt[(size_t)b * HW + pix], 1.0f);
    }
}

// K3: idx_window = argmax(pw, axis=-1), first-max tiebreak
__global__ __launch_bounds__(256) void argmax_kernel(const float* __restrict__ pw, int* __restrict__ idxw)
{
    int t = blockIdx.x * 256 + threadIdx.x;
    if (t >= B * N) return;
    const float* row = pw + (size_t)t * NWIN;
    float best = row[0]; int bi = 0;
    for (int j = 1; j < NWIN; j++) {
        float v = row[j];
        if (v > best) { best = v; bi = j; }
    }
    idxw[t] = bi;
}

// K4: normalize: mp *= 1/(cnt+1e-6) in place; conf = csum/(cnt+1e-6)
__global__ __launch_bounds__(128) void normalize_kernel(
    float* __restrict__ mp, const float* __restrict__ csum,
    const float* __restrict__ cnt, float* __restrict__ conf)
{
    int r = blockIdx.x;
    float inv = 1.0f / (cnt[r] + 1e-6f);
    float* row = mp + (size_t)r * C;
    for (int c = threadIdx.x; c < C; c += 128)
        row[c] *= inv;
    if (threadIdx.x == 0) conf[r] = csum[r] * inv;
}

// K4b: flag-dtyped -> bf16 bits conversion (x pre-convert for MFMA A)
__global__ __launch_bounds__(256) void conv_bf16_kernel(
    const void* __restrict__ src, unsigned short* __restrict__ dst,
    int n, const int* __restrict__ flagp)
{
    const bool f32 = (*flagp != 0);
    int i = (blockIdx.x * 256 + threadIdx.x) * 4;
    if (i + 3 < n) {
        #pragma unroll
        for (int j = 0; j < 4; j++)
            dst[i + j] = f2bf_bits(ldin(src, i + j, f32));
    }
}

// K5: transpose + convert weight W (K,Nn) flag-dtype -> Wt (Nn,K) bf16 bits
__global__ __launch_bounds__(256) void transpose_conv_kernel(
    const void* __restrict__ W, unsigned short* __restrict__ Wt,
    int K, int Nn, const int* __restrict__ flagp)
{
    const bool f32 = (*flagp != 0);
    __shared__ float tile[32][33];
    int n0 = blockIdx.x * 32, k0 = blockIdx.y * 32;
    int tx = threadIdx.x & 31, ty = threadIdx.x >> 5;  // 32 x 8
    #pragma unroll
    for (int i = 0; i < 4; i++)
        tile[ty + i * 8][tx] = ldin(W, (size_t)(k0 + ty + i * 8) * Nn + (n0 + tx), f32);
    __syncthreads();
    #pragma unroll
    for (int i = 0; i < 4; i++)
        Wt[(size_t)(n0 + ty + i * 8) * K + (k0 + tx)] = f2bf_bits(tile[tx][ty + i * 8]);
}

// K6: MFMA GEMM, compile-time A dtype (float -> convert in staging; ushort -> bf16 direct).
// Bt: (Nn,K) bf16 bits. c_mode: 0 = fp32 store, 1 = bf16 store, 2 = flag-dtyped store.
// Tile 128x128, BK=32, 4 waves each owning a 64x64 quadrant (4x4 MFMA 16x16x32).
// LDS row stride 40 halfwords (80 B): 16B-aligned ds_*_b128, 2-way bank aliasing (free).
template <typename AT>
__global__ __launch_bounds__(256) void mfma_gemm_kernel(
    const AT* __restrict__ A,
    const unsigned short* __restrict__ Bt,
    const void* __restrict__ bias,
    void* __restrict__ Co, int c_mode,
    int M, int Nn, int K, float alpha, const int* __restrict__ flagp)
{
    constexpr int SA = 40;  // LDS halfword stride per 32-K row
    const bool f32 = (*flagp != 0);
    const bool store_f32 = (c_mode == 0) || (c_mode == 2 && f32);
    __shared__ unsigned short As[128 * SA];
    __shared__ unsigned short Bs[128 * SA];
    const int t = threadIdx.x;
    const int wave = t >> 6, lane = t & 63;
    const int quad = lane >> 4, l16 = lane & 15;
    const int wm = (wave >> 1) * 64, wn = (wave & 1) * 64;
    const int bm = blockIdx.y * 128, bn = blockIdx.x * 128;

    f32x4 acc[4][4] = {};

    for (int k0 = 0; k0 < K; k0 += 32) {
        #pragma unroll
        for (int ss = 0; ss < 2; ss++) {
            int s = t + ss * 256;
            int row = s >> 2, ch = s & 3;
            int grow = bm + row; if (grow >= M) grow = M - 1;
            if constexpr (std::is_same<AT, float>::value) {
                const float* ga = A + (size_t)grow * K + k0 + ch * 8;
                float4 v0 = *(const float4*)ga;
                float4 v1 = *(const float4*)(ga + 4);
                u16x8 av;
                av[0] = f2bf_bits(v0.x); av[1] = f2bf_bits(v0.y);
                av[2] = f2bf_bits(v0.z); av[3] = f2bf_bits(v0.w);
                av[4] = f2bf_bits(v1.x); av[5] = f2bf_bits(v1.y);
                av[6] = f2bf_bits(v1.z); av[7] = f2bf_bits(v1.w);
                *(u16x8*)&As[row * SA + ch * 8] = av;
            } else {
                *(u16x8*)&As[row * SA + ch * 8] =
                    *(const u16x8*)(A + (size_t)grow * K + k0 + ch * 8);
            }
            *(u16x8*)&Bs[row * SA + ch * 8] =
                *(const u16x8*)(Bt + (size_t)(bn + row) * K + k0 + ch * 8);
        }
        __syncthreads();

        bf16x8 af[4], bf[4];
        #pragma unroll
        for (int i = 0; i < 4; i++) {
            af[i] = *(const bf16x8*)&As[(wm + i * 16 + l16) * SA + quad * 8];
            bf[i] = *(const bf16x8*)&Bs[(wn + i * 16 + l16) * SA + quad * 8];
        }
        #pragma unroll
        for (int i = 0; i < 4; i++)
            #pragma unroll
            for (int j = 0; j < 4; j++)
                acc[i][j] = __builtin_amdgcn_mfma_f32_16x16x32_bf16(af[i], bf[j], acc[i][j], 0, 0, 0);
        __syncthreads();
    }

    // epilogue: C/D layout col=lane&15, row=quad*4+reg
    #pragma unroll
    for (int i = 0; i < 4; i++) {
        int growb = bm + wm + i * 16 + quad * 4;
        #pragma unroll
        for (int j = 0; j < 4; j++) {
            int gcol = bn + wn + j * 16 + l16;
            float bv = ldin(bias, gcol, f32);
            #pragma unroll
            for (int r = 0; r < 4; r++) {
                int grow = growb + r;
                if (grow < M) {
                    float v = (acc[i][j][r] + bv) * alpha;
                    size_t idx = (size_t)grow * Nn + gcol;
                    if (store_f32) ((float*)Co)[idx] = v;
                    else           ((unsigned short*)Co)[idx] = f2bf_bits(v);
                }
            }
        }
    }
}

// K7: window-centric attention v3 — LDS-pipe minimized.
// Grid: B*NWIN*2 blocks; block handles tokens with (n & 1) == par (deterministic split).
// 1024 threads = 16 waves; wave = (half = w>>3, head = w&7); wave processes list
// slots half, half+2, ... Per-wave loop-invariants in registers: k-row fragment
// (lane=key) and v-row fragment (lane=d, from a transposed V tile). q via
// readfirstlane -> wave-uniform scalar loads (SMEM pipe, not LDS). PV via one
// p-store + broadcast float4 reads (conflict-free).
__global__ __launch_bounds__(1024) void attn_win_kernel(
    const float* __restrict__ q,              // (B*N, C) pre-scaled
    const unsigned short* __restrict__ kv,    // (B*HW, 768 halfwords): [k | v]
    const float* __restrict__ conf,           // (B*HW)
    const int* __restrict__ idxw,             // (B*N)
    unsigned short* __restrict__ attno)       // (B*N, C) bf16 bits
{
    constexpr int SK = 392;   // k row stride (u16): 784 B, 16B-aligned, 2-way banks
    __shared__ unsigned short s_k[KWIN * SK];        // 38,416 B  [key][c]
    __shared__ unsigned short s_vt[C * KPAD];        // 43,008 B  [c][key] transposed
    __shared__ float s_p[16][KPAD];                  //  3,584 B  per-wave p vectors
    __shared__ unsigned short s_list[400];           //    800 B
    __shared__ float s_conf[KWIN];
    __shared__ int   s_cnt;

    const int t = threadIdx.x;
    const int blk = blockIdx.x;                 // b*128 + win*2 + par
    const int b   = blk >> 7;
    const int win = (blk >> 1) & 63;
    const int par = blk & 1;
    const int wy = win >> 3, wx = win & 7;

    if (t == 0) s_cnt = 0;
    __syncthreads();
    // member tokens of this parity (deterministic partition across the 2 blocks)
    if (t < N) {
        if (idxw[b * N + t] == win && (t & 1) == par) {
            int slot = atomicAdd(&s_cnt, 1);
            s_list[slot] = (unsigned short)t;
        }
    }
    // stage K rows (row-major) and V transposed; zero V's padded key columns
    const unsigned* kvw = (const unsigned*)kv;
    for (int idx = t; idx < KWIN * 192; idx += 1024) {
        int row = idx / 192, cw = idx % 192;
        int pix = (wy * 7 + row / 7) * Wimg + wx * 7 + row % 7;
        size_t gbase = ((size_t)b * HW + pix) * 384;
        // k word
        *(unsigned*)&s_k[row * SK + cw * 2] = kvw[gbase + cw];
        // v word -> transposed scatter
        unsigned vv = kvw[gbase + 192 + cw];
        int c0 = cw * 2;
        s_vt[(c0 + 0) * KPAD + row] = (unsigned short)(vv & 0xffffu);
        s_vt[(c0 + 1) * KPAD + row] = (unsigned short)(vv >> 16);
    }
    if (t < C) {   // zero pad columns 49..55 of every channel row
        #pragma unroll
        for (int j = KWIN; j < KPAD; j++) s_vt[t * KPAD + j] = 0;
    }
    if (t < KWIN) {
        int pix = (wy * 7 + t / 7) * Wimg + wx * 7 + t % 7;
        s_conf[t] = conf[(size_t)b * HW + pix];
    }
    __syncthreads();

    const int cnt  = s_cnt;
    const int wave = t >> 6;
    const int lane = t & 63;
    const int h    = __builtin_amdgcn_readfirstlane(wave & 7);
    const int half = wave >> 3;

    // zero p pad slots once (wave-private)
    if (lane >= KWIN && lane < KPAD) s_p[wave][lane] = 0.0f;

    // loop-invariant register fragments
    const int krow = (lane < KWIN) ? lane : 0;
    u16x8 kf[6];
    #pragma unroll
    for (int j = 0; j < 6; j++)
        kf[j] = *(const u16x8*)&s_k[krow * SK + h * D + j * 8];
    const int vrow = h * D + ((lane < D) ? lane : 0);
    u16x8 vf[7];
    #pragma unroll
    for (int j = 0; j < 7; j++)
        vf[j] = *(const u16x8*)&s_vt[vrow * KPAD + j * 8];
    const float confk = (lane < KWIN) ? s_conf[lane] : 0.0f;

    for (int ti = half; ti < cnt; ti += 2) {
        const int n0 = __builtin_amdgcn_readfirstlane((int)s_list[ti]);
        const size_t bn = (size_t)b * N + n0;
        const float* qrow = q + bn * C + h * D;   // wave-uniform -> s_load

        // logits (lane = key)
        float l = -INFINITY;
        if (lane < KWIN) {
            float acc = confk;
            #pragma unroll
            for (int j = 0; j < 6; j++)
                #pragma unroll
                for (int e = 0; e < 8; e++)
                    acc += qrow[j * 8 + e] * bfbits2f(kf[j][e]);
            l = acc;
        }
        // in-wave softmax over 49 active lanes
        float m = l;
        #pragma unroll
        for (int off = 32; off >= 1; off >>= 1) m = fmaxf(m, __shfl_xor(m, off));
        float e = (lane < KWIN) ? expf(l - m) : 0.0f;
        float ssum = e;
        #pragma unroll
        for (int off = 32; off >= 1; off >>= 1) ssum += __shfl_xor(ssum, off);
        if (lane < KWIN) s_p[wave][lane] = e / ssum;
        __builtin_amdgcn_wave_barrier();

        // PV (lane = d): p via broadcast float4 reads, v in registers
        float acc = 0.0f;
        const float4* pv4 = (const float4*)&s_p[wave][0];
        #pragma unroll
        for (int j = 0; j < KPAD / 4; j++) {
            float4 p4 = pv4[j];
            acc += p4.x * bfbits2f(vf[(j * 4 + 0) / 8][(j * 4 + 0) % 8]);
            acc += p4.y * bfbits2f(vf[(j * 4 + 1) / 8][(j * 4 + 1) % 8]);
            acc += p4.z * bfbits2f(vf[(j * 4 + 2) / 8][(j * 4 + 2) % 8]);
            acc += p4.w * bfbits2f(vf[(j * 4 + 3) / 8][(j * 4 + 3) % 8]);
        }
        if (lane < D) attno[bn * C + h * D + lane] = f2bf_bits(acc);
    }
}

extern "C" void kernel_launch(void* const* d_in, const int* in_sizes, int n_in,
                              void* d_out, int out_size, void* d_ws, size_t ws_size,
                              hipStream_t stream) {
    if (ws_size < WS_BYTES_NEEDED) return;  // visible failure if ws too small

    const void* x        = d_in[0];
    const void* loc      = d_in[1];
    const int*  idx_agg  = (const int*)d_in[2];
    const void* agg_w    = d_in[3];
    const void* x_source = d_in[4];
    const int*  idx_asrc = (const int*)d_in[5];
    const void* conf_src = d_in[6];
    int wb = 9;
    if (!(n_in >= 15 && in_sizes[7] == 1 && in_sizes[8] == 1)) wb = 7;
    const void* q_w    = d_in[wb + 0];
    const void* q_b    = d_in[wb + 1];
    const void* kv_w   = d_in[wb + 2];
    const void* kv_b   = d_in[wb + 3];
    const void* proj_w = d_in[wb + 4];
    const void* proj_b = d_in[wb + 5];

    float* ws   = (float*)d_ws;
    float* pw   = ws + OFF_PW;
    float* mp   = ws + OFF_MP;
    float* csum = ws + OFF_CSUM;
    float* cnt  = ws + OFF_CNT;
    float* q    = ws + OFF_Q;
    float* conf = ws + OFF_CONF;
    int*   idxw = (int*)(ws + OFF_IDXW);
    unsigned short* attno = (unsigned short*)(ws + OFF_ATTNO);
    unsigned short* kv = (unsigned short*)(ws + OFF_KV_F);
    unsigned short* kvwt   = (unsigned short*)((char*)d_ws + OFF_KVWT_BYTE);
    unsigned short* qwt    = (unsigned short*)((char*)d_ws + OFF_QWT_BYTE);
    unsigned short* projwt = (unsigned short*)((char*)d_ws + OFF_PROJWT_BYTE);
    int* flag = (int*)((char*)d_ws + OFF_FLAG_BYTE);
    unsigned short* xbf = (unsigned short*)((char*)d_ws + OFF_XBF_BYTE);

    // dtype sniff
    sniff_kernel<<<1, 64, 0, stream>>>((const unsigned short*)q_w, flag);
    // zero accumulators
    hipMemsetAsync(ws, 0, ZERO_FLOATS * sizeof(float), stream);
    // pre-transpose weights to (N,K) bf16 for MFMA B-operand
    transpose_conv_kernel<<<dim3(C2 / 32, C / 32), 256, 0, stream>>>(kv_w, kvwt, C, C2, flag);
    transpose_conv_kernel<<<dim3(C / 32, C / 32), 256, 0, stream>>>(q_w, qwt, C, C, flag);
    transpose_conv_kernel<<<dim3(C / 32, C / 32), 256, 0, stream>>>(proj_w, projwt, C, C, flag);
    // pre-convert x to bf16 for MFMA A-operand
    conv_bf16_kernel<<<(B * N * C / 4 + 255) / 256, 256, 0, stream>>>(x, xbf, B * N * C, flag);

    scatter_pw_kernel<<<(B * NSRC + 255) / 256, 256, 0, stream>>>(loc, idx_agg, agg_w, pw, flag);
    scatter_map_kernel<<<B * NSRC, 128, 0, stream>>>(loc, idx_asrc, x_source, conf_src, mp, csum, cnt, flag);
    argmax_kernel<<<(B * N + 255) / 256, 256, 0, stream>>>(pw, idxw);
    normalize_kernel<<<B * HW, 128, 0, stream>>>(mp, csum, cnt, conf);

    const float scale = (float)(1.0 / sqrt((double)D));
    // q = (x @ q_w + q_b) * scale   [MFMA, bf16 A, fp32 out]
    mfma_gemm_kernel<unsigned short><<<dim3(C / 128, (B * N + 127) / 128), 256, 0, stream>>>(
        xbf, qwt, q_b, q, 0, B * N, C, C, scale, flag);
    // kv = mp @ kv_w + kv_b         [MFMA, fp32 A vectorized, bf16 out]
    mfma_gemm_kernel<float><<<dim3(C2 / 128, (B * HW) / 128), 256, 0, stream>>>(
        mp, kvwt, kv_b, kv, 1, B * HW, C2, C, 1.0f, flag);
    // attention (window-centric v3, 2-way token split)
    attn_win_kernel<<<B * NWIN * 2, 1024, 0, stream>>>(q, kv, conf, idxw, attno);
    // out = attno @ proj_w + proj_b [MFMA, bf16 A, flag-dtyped out]
    mfma_gemm_kernel<unsigned short><<<dim3(C / 128, (B * N + 127) / 128), 256, 0, stream>>>(
        attno, projwt, proj_b, d_out, 2, B * N, C, C, 1.0f, flag);

    (void)out_size;
}

// Round 9
// 247.303 us; speedup vs baseline: 2.1975x; 1.0314x over previous
//
#include <hip/hip_runtime.h>
#include <hip/hip_bf16.h>
#include <cstdint>
#include <type_traits>

// Problem constants (fixed by setup_inputs)
constexpr int B    = 4;
constexpr int N    = 784;    // tokens
constexpr int C    = 384;
constexpr int NH   = 8;
constexpr int D    = 48;     // C/NH
constexpr int Himg = 56;
constexpr int Wimg = 56;
constexpr int HW   = 3136;   // Himg*Wimg
constexpr int NSRC = 3136;   // N0
constexpr int NWIN = 64;     // 8x8 windows of 7x7
constexpr int KWIN = 49;     // keys per window
constexpr int KPAD = 56;     // padded key count for p vectors
constexpr int C2   = 2 * C;  // 768

// ---- workspace layout (float units unless noted) ----
constexpr size_t OFF_PW      = 0;                          // B*N*NWIN
constexpr size_t SZ_PW       = (size_t)B * N * NWIN;
constexpr size_t OFF_MP      = OFF_PW + SZ_PW;             // B*HW*C fp32
constexpr size_t SZ_MP       = (size_t)B * HW * C;
constexpr size_t OFF_CSUM    = OFF_MP + SZ_MP;             // B*HW
constexpr size_t SZ_CSUM     = (size_t)B * HW;
constexpr size_t OFF_CNT     = OFF_CSUM + SZ_CSUM;         // B*HW
constexpr size_t SZ_CNT      = (size_t)B * HW;
constexpr size_t ZERO_FLOATS = OFF_CNT + SZ_CNT;           // 5,042,688
// non-zeroed:
constexpr size_t OFF_Q       = ZERO_FLOATS;                // B*N*C fp32
constexpr size_t SZ_Q        = (size_t)B * N * C;
constexpr size_t OFF_CONF    = OFF_Q + SZ_Q;               // B*HW fp32
constexpr size_t SZ_CONF     = (size_t)B * HW;
constexpr size_t OFF_IDXW    = OFF_CONF + SZ_CONF;         // B*N ints
constexpr size_t SZ_IDXW     = (size_t)B * N;
constexpr size_t OFF_ATTNO   = OFF_IDXW + SZ_IDXW;         // B*N*C, stored as bf16
constexpr size_t SZ_ATTNO    = (size_t)B * N * C;
constexpr size_t OFF_KV_F    = OFF_ATTNO + SZ_ATTNO;       // kv bf16
constexpr size_t SZ_KV_BF16  = (size_t)B * HW * C2;
constexpr size_t MAIN_BYTES  = OFF_KV_F * 4 + SZ_KV_BF16 * 2;  // 49,134,848
// bf16 side buffers (built per launch):
constexpr size_t OFF_KVWT_BYTE  = MAIN_BYTES;                      // (768,384) bf16
constexpr size_t SZ_KVWT        = (size_t)C2 * C;
constexpr size_t OFF_QWT_BYTE   = OFF_KVWT_BYTE + SZ_KVWT * 2;     // (384,384) bf16
constexpr size_t SZ_QWT         = (size_t)C * C;
constexpr size_t OFF_PROJWT_BYTE= OFF_QWT_BYTE + SZ_QWT * 2;       // (384,384) bf16
constexpr size_t SZ_PROJWT      = (size_t)C * C;
constexpr size_t OFF_FLAG_BYTE  = OFF_PROJWT_BYTE + SZ_PROJWT * 2;
constexpr size_t OFF_XBF_BYTE   = OFF_FLAG_BYTE + 16;              // (B*N,C) bf16
constexpr size_t SZ_XBF         = (size_t)B * N * C;
constexpr size_t WS_BYTES_NEEDED = OFF_XBF_BYTE + SZ_XBF * 2;      // ~52.7 MB

typedef __attribute__((ext_vector_type(8))) short bf16x8;          // MFMA A/B frag
typedef __attribute__((ext_vector_type(8))) unsigned short u16x8;  // raw staging
typedef __attribute__((ext_vector_type(4))) float f32x4;           // MFMA C/D frag

__device__ __forceinline__ float b2f(__hip_bfloat16 x) { return __bfloat162float(x); }
__device__ __forceinline__ unsigned short f2bf_bits(float f) {
    __hip_bfloat16 h = __float2bfloat16(f);
    return *reinterpret_cast<unsigned short*>(&h);
}
__device__ __forceinline__ float bfbits2f(unsigned short u) {
    return __uint_as_float(((unsigned)u) << 16);
}
__device__ __forceinline__ float bflo(unsigned w) { return __uint_as_float(w << 16); }
__device__ __forceinline__ float bfhi(unsigned w) { return __uint_as_float(w & 0xffff0000u); }

// Flag-dispatched input load: f32=true -> fp32 buffer, else bf16 buffer.
__device__ __forceinline__ float ldin(const void* p, size_t i, bool f32) {
    if (f32) return ((const float*)p)[i];
    return __bfloat162float(((const __hip_bfloat16*)p)[i]);
}

// grid index per reference _grid_idx (fp32, RNE rounding == jnp.round)
__device__ __forceinline__ void grid_idx(float lx, float ly, int& xg, int& yg) {
    float xf = 0.5f * (lx + 1.0f) * (float)Wimg - 0.5f;
    float yf = 0.5f * (ly + 1.0f) * (float)Himg - 0.5f;
    int x = (int)rintf(xf);
    int y = (int)rintf(yf);
    xg = min(max(x, 0), Wimg - 1);
    yg = min(max(y, 0), Himg - 1);
}

// K0: dtype sniffer (fp32 vs bf16 inputs).
__global__ __launch_bounds__(64) void sniff_kernel(const unsigned short* __restrict__ qw_bits,
                                                   int* __restrict__ flag) {
    int t = threadIdx.x;
    int cnt = 0;
    #pragma unroll
    for (int i = 0; i < 8; i++) {
        unsigned u = qw_bits[t * 8 + i];
        float v = __uint_as_float(u << 16);
        if (fabsf(v) > 4.0f) cnt++;
    }
    #pragma unroll
    for (int off = 32; off >= 1; off >>= 1) cnt += __shfl_xor(cnt, off);
    if (t == 0) *flag = (cnt > 8) ? 1 : 0;
}

// K1: pw[b, idx_agg[b,p], win(p)] += agg_weight[b,p]
__global__ __launch_bounds__(256) void scatter_pw_kernel(
    const void* __restrict__ loc, const int* __restrict__ idx_agg,
    const void* __restrict__ agg_w, float* __restrict__ pw,
    const int* __restrict__ flagp)
{
    const bool f32 = (*flagp != 0);
    int p = blockIdx.x * 256 + threadIdx.x;
    if (p >= B * NSRC) return;
    int b = p / NSRC;
    float lx = ldin(loc, (size_t)p * 2 + 0, f32);
    float ly = ldin(loc, (size_t)p * 2 + 1, f32);
    int xg, yg; grid_idx(lx, ly, xg, yg);
    int win = (yg / 7) * 8 + (xg / 7);
    int n = idx_agg[p];
    float w = ldin(agg_w, p, f32);
    atomicAdd(&pw[((size_t)b * N + n) * NWIN + win], w);
}

// K2: token2map scatter
__global__ __launch_bounds__(128) void scatter_map_kernel(
    const void* __restrict__ loc, const int* __restrict__ idx_agg_src,
    const void* __restrict__ x_source, const void* __restrict__ conf_src,
    float* __restrict__ mp, float* __restrict__ csum, float* __restrict__ cnt,
    const int* __restrict__ flagp)
{
    const bool f32 = (*flagp != 0);
    int p = blockIdx.x;
    int b = p / NSRC;
    float lx = ldin(loc, (size_t)p * 2 + 0, f32);
    float ly = ldin(loc, (size_t)p * 2 + 1, f32);
    int xg, yg; grid_idx(lx, ly, xg, yg);
    int pix = yg * Wimg + xg;
    int s = idx_agg_src[p];
    size_t srow = ((size_t)b * N + s) * C;
    float* drow = mp + ((size_t)b * HW + pix) * C;
    for (int c = threadIdx.x; c < C; c += 128)
        atomicAdd(&drow[c], ldin(x_source, srow + c, f32));
    if (threadIdx.x == 0) {
        atomicAdd(&csum[(size_t)b * HW + pix], ldin(conf_src, (size_t)b * N + s, f32));
        atomicAdd(&cnt[(size_t)b * HW + pix], 1.0f);
    }
}

// K3: idx_window = argmax(pw, axis=-1), first-max tiebreak
__global__ __launch_bounds__(256) void argmax_kernel(const float* __restrict__ pw, int* __restrict__ idxw)
{
    int t = blockIdx.x * 256 + threadIdx.x;
    if (t >= B * N) return;
    const float* row = pw + (size_t)t * NWIN;
    float best = row[0]; int bi = 0;
    for (int j = 1; j < NWIN; j++) {
        float v = row[j];
        if (v > best) { best = v; bi = j; }
    }
    idxw[t] = bi;
}

// K4: normalize: mp *= 1/(cnt+1e-6) in place; conf = csum/(cnt+1e-6)
__global__ __launch_bounds__(128) void normalize_kernel(
    float* __restrict__ mp, const float* __restrict__ csum,
    const float* __restrict__ cnt, float* __restrict__ conf)
{
    int r = blockIdx.x;
    float inv = 1.0f / (cnt[r] + 1e-6f);
    float* row = mp + (size_t)r * C;
    for (int c = threadIdx.x; c < C; c += 128)
        row[c] *= inv;
    if (threadIdx.x == 0) conf[r] = csum[r] * inv;
}

// K4b: flag-dtyped -> bf16 bits conversion (x pre-convert for MFMA A)
__global__ __launch_bounds__(256) void conv_bf16_kernel(
    const void* __restrict__ src, unsigned short* __restrict__ dst,
    int n, const int* __restrict__ flagp)
{
    const bool f32 = (*flagp != 0);
    int i = (blockIdx.x * 256 + threadIdx.x) * 4;
    if (i + 3 < n) {
        #pragma unroll
        for (int j = 0; j < 4; j++)
            dst[i + j] = f2bf_bits(ldin(src, i + j, f32));
    }
}

// K5: transpose + convert weight W (K,Nn) flag-dtype -> Wt (Nn,K) bf16 bits
__global__ __launch_bounds__(256) void transpose_conv_kernel(
    const void* __restrict__ W, unsigned short* __restrict__ Wt,
    int K, int Nn, const int* __restrict__ flagp)
{
    const bool f32 = (*flagp != 0);
    __shared__ float tile[32][33];
    int n0 = blockIdx.x * 32, k0 = blockIdx.y * 32;
    int tx = threadIdx.x & 31, ty = threadIdx.x >> 5;  // 32 x 8
    #pragma unroll
    for (int i = 0; i < 4; i++)
        tile[ty + i * 8][tx] = ldin(W, (size_t)(k0 + ty + i * 8) * Nn + (n0 + tx), f32);
    __syncthreads();
    #pragma unroll
    for (int i = 0; i < 4; i++)
        Wt[(size_t)(n0 + ty + i * 8) * K + (k0 + tx)] = f2bf_bits(tile[tx][ty + i * 8]);
}

// K6: MFMA GEMM, compile-time A dtype (float -> convert in staging; ushort -> bf16 direct).
// Bt: (Nn,K) bf16 bits. c_mode: 0 = fp32 store, 1 = bf16 store, 2 = flag-dtyped store.
// Tile 128x128, BK=32, 4 waves each owning a 64x64 quadrant (4x4 MFMA 16x16x32).
// LDS row stride 40 halfwords (80 B): 16B-aligned ds_*_b128, 2-way bank aliasing (free).
template <typename AT>
__global__ __launch_bounds__(256) void mfma_gemm_kernel(
    const AT* __restrict__ A,
    const unsigned short* __restrict__ Bt,
    const void* __restrict__ bias,
    void* __restrict__ Co, int c_mode,
    int M, int Nn, int K, float alpha, const int* __restrict__ flagp)
{
    constexpr int SA = 40;  // LDS halfword stride per 32-K row
    const bool f32 = (*flagp != 0);
    const bool store_f32 = (c_mode == 0) || (c_mode == 2 && f32);
    __shared__ unsigned short As[128 * SA];
    __shared__ unsigned short Bs[128 * SA];
    const int t = threadIdx.x;
    const int wave = t >> 6, lane = t & 63;
    const int quad = lane >> 4, l16 = lane & 15;
    const int wm = (wave >> 1) * 64, wn = (wave & 1) * 64;
    const int bm = blockIdx.y * 128, bn = blockIdx.x * 128;

    f32x4 acc[4][4] = {};

    for (int k0 = 0; k0 < K; k0 += 32) {
        #pragma unroll
        for (int ss = 0; ss < 2; ss++) {
            int s = t + ss * 256;
            int row = s >> 2, ch = s & 3;
            int grow = bm + row; if (grow >= M) grow = M - 1;
            if constexpr (std::is_same<AT, float>::value) {
                const float* ga = A + (size_t)grow * K + k0 + ch * 8;
                float4 v0 = *(const float4*)ga;
                float4 v1 = *(const float4*)(ga + 4);
                u16x8 av;
                av[0] = f2bf_bits(v0.x); av[1] = f2bf_bits(v0.y);
                av[2] = f2bf_bits(v0.z); av[3] = f2bf_bits(v0.w);
                av[4] = f2bf_bits(v1.x); av[5] = f2bf_bits(v1.y);
                av[6] = f2bf_bits(v1.z); av[7] = f2bf_bits(v1.w);
                *(u16x8*)&As[row * SA + ch * 8] = av;
            } else {
                *(u16x8*)&As[row * SA + ch * 8] =
                    *(const u16x8*)(A + (size_t)grow * K + k0 + ch * 8);
            }
            *(u16x8*)&Bs[row * SA + ch * 8] =
                *(const u16x8*)(Bt + (size_t)(bn + row) * K + k0 + ch * 8);
        }
        __syncthreads();

        bf16x8 af[4], bf[4];
        #pragma unroll
        for (int i = 0; i < 4; i++) {
            af[i] = *(const bf16x8*)&As[(wm + i * 16 + l16) * SA + quad * 8];
            bf[i] = *(const bf16x8*)&Bs[(wn + i * 16 + l16) * SA + quad * 8];
        }
        #pragma unroll
        for (int i = 0; i < 4; i++)
            #pragma unroll
            for (int j = 0; j < 4; j++)
                acc[i][j] = __builtin_amdgcn_mfma_f32_16x16x32_bf16(af[i], bf[j], acc[i][j], 0, 0, 0);
        __syncthreads();
    }

    // epilogue: C/D layout col=lane&15, row=quad*4+reg
    #pragma unroll
    for (int i = 0; i < 4; i++) {
        int growb = bm + wm + i * 16 + quad * 4;
        #pragma unroll
        for (int j = 0; j < 4; j++) {
            int gcol = bn + wn + j * 16 + l16;
            float bv = ldin(bias, gcol, f32);
            #pragma unroll
            for (int r = 0; r < 4; r++) {
                int grow = growb + r;
                if (grow < M) {
                    float v = (acc[i][j][r] + bv) * alpha;
                    size_t idx = (size_t)grow * Nn + gcol;
                    if (store_f32) ((float*)Co)[idx] = v;
                    else           ((unsigned short*)Co)[idx] = f2bf_bits(v);
                }
            }
        }
    }
}

// K7: window-centric attention v4 — head-split blocks, no spills, no dup staging.
// Grid: B*NWIN*4; block handles head pair par = blk&3 (heads 2par, 2par+1).
// 512 threads = 8 waves; wave = (quarter = w>>1, head' = w&1); wave processes
// list slots quarter, quarter+4, ... Loop-invariant register fragments:
// k-row (lane=key, 3x uint4 from s_k) and v-col (lane=d, 28x u32 from transposed
// s_vt). q via wave-uniform scalar loads. PV via p-store + broadcast float4 reads.
// __launch_bounds__(512,4) -> 128 VGPR budget: fragments (~52 VGPR) stay in regs.
__global__ __launch_bounds__(512, 4) void attn_win_kernel(
    const float* __restrict__ q,              // (B*N, C) pre-scaled
    const unsigned short* __restrict__ kv,    // (B*HW, 768 halfwords): [k | v]
    const float* __restrict__ conf,           // (B*HW)
    const int* __restrict__ idxw,             // (B*N)
    unsigned short* __restrict__ attno)       // (B*N, C) bf16 bits
{
    constexpr int SK  = 104;  // k row stride (u16): 208 B, 16B-aligned
    constexpr int SVT = 58;   // vt row stride (u16): 116 B, 4B-aligned
    constexpr int CH  = 2 * D;   // 96 channels per block (2 heads)
    __shared__ unsigned short s_k[KWIN * SK];    // 10,192 B  [key][c']
    __shared__ unsigned short s_vt[CH * SVT];    // 11,136 B  [c'][key]
    __shared__ float s_p[8][KPAD];               //  1,792 B  per-wave p vectors
    __shared__ unsigned short s_list[N];         //  1,568 B
    __shared__ float s_conf[KWIN];
    __shared__ int   s_cnt;

    const int t   = threadIdx.x;
    const int blk = blockIdx.x;                 // b*256 + win*4 + par
    const int b   = blk >> 8;
    const int win = (blk >> 2) & 63;
    const int par = blk & 3;                    // head pair: heads 2par, 2par+1
    const int wy = win >> 3, wx = win & 7;

    if (t == 0) s_cnt = 0;
    __syncthreads();
    // member tokens (order irrelevant: blocks of different par write disjoint heads)
    for (int n = t; n < N; n += 512) {
        if (idxw[b * N + n] == win) {
            int slot = atomicAdd(&s_cnt, 1);
            s_list[slot] = (unsigned short)n;
        }
    }
    // stage this head-pair's k slice (row-major) and v slice (transposed)
    const unsigned* kvw = (const unsigned*)kv;
    for (int idx = t; idx < KWIN * (CH / 2); idx += 512) {
        int row = idx / (CH / 2), cw = idx % (CH / 2);   // cw = word within 96-ch slice
        int pix = (wy * 7 + row / 7) * Wimg + wx * 7 + row % 7;
        size_t gbase = ((size_t)b * HW + pix) * 384 + par * (CH / 2);
        // k word -> row-major (conflict-free: consecutive cw)
        *(unsigned*)&s_k[row * SK + cw * 2] = kvw[gbase + cw];
        // v word -> transposed scatter (stride 58 words: ~4-way, tiny volume)
        unsigned vv = kvw[gbase + 192 + cw];
        int c0 = cw * 2;
        s_vt[(c0 + 0) * SVT + row] = (unsigned short)(vv & 0xffffu);
        s_vt[(c0 + 1) * SVT + row] = (unsigned short)(vv >> 16);
    }
    if (t < CH) {   // zero pad key columns 49..55
        #pragma unroll
        for (int j = KWIN; j < KPAD; j++) s_vt[t * SVT + j] = 0;
    }
    if (t < KWIN) {
        int pix = (wy * 7 + t / 7) * Wimg + wx * 7 + t % 7;
        s_conf[t] = conf[(size_t)b * HW + pix];
    }
    __syncthreads();

    const int cnt   = s_cnt;
    const int wave  = t >> 6;
    const int lane  = t & 63;
    const int hloc  = __builtin_amdgcn_readfirstlane(wave & 1);  // local head 0/1
    const int quart = wave >> 1;                                  // 0..3
    const int h     = par * 2 + hloc;                             // global head

    // zero p pad slots once (wave-private; only pads, never rewritten)
    if (lane >= KWIN && lane < KPAD) s_p[wave][lane] = 0.0f;

    // loop-invariant register fragments
    const int krow = (lane < KWIN) ? lane : 0;
    uint4 kf[3];   // 48 channels = 96 B = 3 x b128
    #pragma unroll
    for (int j = 0; j < 3; j++)
        kf[j] = *(const uint4*)&s_k[krow * SK + hloc * D + j * 16];
    const int dl = (lane < D) ? lane : 0;
    unsigned vw[28];  // 56 key slots (u16) for channel row hloc*D + dl
    {
        const unsigned short* vrow = &s_vt[(hloc * D + dl) * SVT];
        #pragma unroll
        for (int j = 0; j < 28; j++) vw[j] = *(const unsigned*)&vrow[j * 2];
    }
    const float confk = (lane < KWIN) ? s_conf[lane] : 0.0f;

    for (int ti = quart; ti < cnt; ti += 4) {
        const int n0 = __builtin_amdgcn_readfirstlane((int)s_list[ti]);
        const size_t bn = (size_t)b * N + n0;
        const float* qrow = q + bn * C + h * D;   // wave-uniform -> scalar loads

        // logits (lane = key): 48-ch dot from registers
        float l = -INFINITY;
        if (lane < KWIN) {
            float acc = confk;
            #pragma unroll
            for (int j = 0; j < 3; j++) {
                const int c = j * 16;
                acc += qrow[c +  0] * bflo(kf[j].x) + qrow[c +  1] * bfhi(kf[j].x);
                acc += qrow[c +  2] * bflo(kf[j].y) + qrow[c +  3] * bfhi(kf[j].y);
                acc += qrow[c +  4] * bflo(kf[j].z) + qrow[c +  5] * bfhi(kf[j].z);
                acc += qrow[c +  6] * bflo(kf[j].w) + qrow[c +  7] * bfhi(kf[j].w);
                uint4 k2 = *(const uint4*)&s_k[krow * SK + hloc * D + j * 16 + 8];
                acc += qrow[c +  8] * bflo(k2.x) + qrow[c +  9] * bfhi(k2.x);
                acc += qrow[c + 10] * bflo(k2.y) + qrow[c + 11] * bfhi(k2.y);
                acc += qrow[c + 12] * bflo(k2.z) + qrow[c + 13] * bfhi(k2.z);
                acc += qrow[c + 14] * bflo(k2.w) + qrow[c + 15] * bfhi(k2.w);
            }
            l = acc;
        }
        // in-wave softmax over 49 active lanes
        float m = l;
        #pragma unroll
        for (int off = 32; off >= 1; off >>= 1) m = fmaxf(m, __shfl_xor(m, off));
        float e = (lane < KWIN) ? expf(l - m) : 0.0f;
        float ssum = e;
        #pragma unroll
        for (int off = 32; off >= 1; off >>= 1) ssum += __shfl_xor(ssum, off);
        if (lane < KWIN) s_p[wave][lane] = e / ssum;
        __builtin_amdgcn_wave_barrier();

        // PV (lane = d): p via broadcast float4 reads, v from registers
        float acc = 0.0f;
        const float4* pv4 = (const float4*)&s_p[wave][0];
        #pragma unroll
        for (int j = 0; j < KPAD / 4; j++) {
            float4 p4 = pv4[j];
            unsigned w0 = vw[j * 2], w1 = vw[j * 2 + 1];
            acc += p4.x * bflo(w0) + p4.y * bfhi(w0);
            acc += p4.z * bflo(w1) + p4.w * bfhi(w1);
        }
        if (lane < D) attno[bn * C + h * D + lane] = f2bf_bits(acc);
    }
}

extern "C" void kernel_launch(void* const* d_in, const int* in_sizes, int n_in,
                              void* d_out, int out_size, void* d_ws, size_t ws_size,
                              hipStream_t stream) {
    if (ws_size < WS_BYTES_NEEDED) return;  // visible failure if ws too small

    const void* x        = d_in[0];
    const void* loc      = d_in[1];
    const int*  idx_agg  = (const int*)d_in[2];
    const void* agg_w    = d_in[3];
    const void* x_source = d_in[4];
    const int*  idx_asrc = (const int*)d_in[5];
    const void* conf_src = d_in[6];
    int wb = 9;
    if (!(n_in >= 15 && in_sizes[7] == 1 && in_sizes[8] == 1)) wb = 7;
    const void* q_w    = d_in[wb + 0];
    const void* q_b    = d_in[wb + 1];
    const void* kv_w   = d_in[wb + 2];
    const void* kv_b   = d_in[wb + 3];
    const void* proj_w = d_in[wb + 4];
    const void* proj_b = d_in[wb + 5];

    float* ws   = (float*)d_ws;
    float* pw   = ws + OFF_PW;
    float* mp   = ws + OFF_MP;
    float* csum = ws + OFF_CSUM;
    float* cnt  = ws + OFF_CNT;
    float* q    = ws + OFF_Q;
    float* conf = ws + OFF_CONF;
    int*   idxw = (int*)(ws + OFF_IDXW);
    unsigned short* attno = (unsigned short*)(ws + OFF_ATTNO);
    unsigned short* kv = (unsigned short*)(ws + OFF_KV_F);
    unsigned short* kvwt   = (unsigned short*)((char*)d_ws + OFF_KVWT_BYTE);
    unsigned short* qwt    = (unsigned short*)((char*)d_ws + OFF_QWT_BYTE);
    unsigned short* projwt = (unsigned short*)((char*)d_ws + OFF_PROJWT_BYTE);
    int* flag = (int*)((char*)d_ws + OFF_FLAG_BYTE);
    unsigned short* xbf = (unsigned short*)((char*)d_ws + OFF_XBF_BYTE);

    // dtype sniff
    sniff_kernel<<<1, 64, 0, stream>>>((const unsigned short*)q_w, flag);
    // zero accumulators
    hipMemsetAsync(ws, 0, ZERO_FLOATS * sizeof(float), stream);
    // pre-transpose weights to (N,K) bf16 for MFMA B-operand
    transpose_conv_kernel<<<dim3(C2 / 32, C / 32), 256, 0, stream>>>(kv_w, kvwt, C, C2, flag);
    transpose_conv_kernel<<<dim3(C / 32, C / 32), 256, 0, stream>>>(q_w, qwt, C, C, flag);
    transpose_conv_kernel<<<dim3(C / 32, C / 32), 256, 0, stream>>>(proj_w, projwt, C, C, flag);
    // pre-convert x to bf16 for MFMA A-operand
    conv_bf16_kernel<<<(B * N * C / 4 + 255) / 256, 256, 0, stream>>>(x, xbf, B * N * C, flag);

    scatter_pw_kernel<<<(B * NSRC + 255) / 256, 256, 0, stream>>>(loc, idx_agg, agg_w, pw, flag);
    scatter_map_kernel<<<B * NSRC, 128, 0, stream>>>(loc, idx_asrc, x_source, conf_src, mp, csum, cnt, flag);
    argmax_kernel<<<(B * N + 255) / 256, 256, 0, stream>>>(pw, idxw);
    normalize_kernel<<<B * HW, 128, 0, stream>>>(mp, csum, cnt, conf);

    const float scale = (float)(1.0 / sqrt((double)D));
    // q = (x @ q_w + q_b) * scale   [MFMA, bf16 A, fp32 out]
    mfma_gemm_kernel<unsigned short><<<dim3(C / 128, (B * N + 127) / 128), 256, 0, stream>>>(
        xbf, qwt, q_b, q, 0, B * N, C, C, scale, flag);
    // kv = mp @ kv_w + kv_b         [MFMA, fp32 A vectorized, bf16 out]
    mfma_gemm_kernel<float><<<dim3(C2 / 128, (B * HW) / 128), 256, 0, stream>>>(
        mp, kvwt, kv_b, kv, 1, B * HW, C2, C, 1.0f, flag);
    // attention (window-centric v4, head-split blocks)
    attn_win_kernel<<<B * NWIN * 4, 512, 0, stream>>>(q, kv, conf, idxw, attno);
    // out = attno @ proj_w + proj_b [MFMA, bf16 A, flag-dtyped out]
    mfma_gemm_kernel<unsigned short><<<dim3(C / 128, (B * N + 127) / 128), 256, 0, stream>>>(
        attno, projwt, proj_b, d_out, 2, B * N, C, C, 1.0f, flag);

    (void)out_size;
}

// Round 10
// 237.018 us; speedup vs baseline: 2.2928x; 1.0434x over previous
//
#include <hip/hip_runtime.h>
#include <hip/hip_bf16.h>
#include <cstdint>
#include <type_traits>

// Problem constants (fixed by setup_inputs)
constexpr int B    = 4;
constexpr int N    = 784;    // tokens
constexpr int C    = 384;
constexpr int NH   = 8;
constexpr int D    = 48;     // C/NH
constexpr int Himg = 56;
constexpr int Wimg = 56;
constexpr int HW   = 3136;   // Himg*Wimg
constexpr int NSRC = 3136;   // N0
constexpr int NWIN = 64;     // 8x8 windows of 7x7
constexpr int KWIN = 49;     // keys per window
constexpr int KPAD = 56;     // padded key count for p vectors
constexpr int C2   = 2 * C;  // 768

// ---- workspace layout (float units unless noted) ----
constexpr size_t OFF_PW      = 0;                          // B*N*NWIN
constexpr size_t SZ_PW       = (size_t)B * N * NWIN;
constexpr size_t OFF_MP      = OFF_PW + SZ_PW;             // B*HW*C fp32 (raw sums)
constexpr size_t SZ_MP       = (size_t)B * HW * C;
constexpr size_t OFF_CSUM    = OFF_MP + SZ_MP;             // B*HW
constexpr size_t SZ_CSUM     = (size_t)B * HW;
constexpr size_t OFF_CNT     = OFF_CSUM + SZ_CSUM;         // B*HW
constexpr size_t SZ_CNT      = (size_t)B * HW;
constexpr size_t ZERO_FLOATS = OFF_CNT + SZ_CNT;           // 5,042,688 (divisible by 4)
// non-zeroed:
constexpr size_t OFF_Q       = ZERO_FLOATS;                // B*N*C fp32
constexpr size_t SZ_Q        = (size_t)B * N * C;
constexpr size_t OFF_CONF    = OFF_Q + SZ_Q;               // (unused now, kept for layout)
constexpr size_t SZ_CONF     = (size_t)B * HW;
constexpr size_t OFF_IDXW    = OFF_CONF + SZ_CONF;         // B*N ints
constexpr size_t SZ_IDXW     = (size_t)B * N;
constexpr size_t OFF_ATTNO   = OFF_IDXW + SZ_IDXW;         // B*N*C, bf16
constexpr size_t SZ_ATTNO    = (size_t)B * N * C;
constexpr size_t OFF_KV_F    = OFF_ATTNO + SZ_ATTNO;       // kv bf16
constexpr size_t SZ_KV_BF16  = (size_t)B * HW * C2;
constexpr size_t MAIN_BYTES  = OFF_KV_F * 4 + SZ_KV_BF16 * 2;  // 49,134,848
// bf16 side buffers (built per launch):
constexpr size_t OFF_KVWT_BYTE  = MAIN_BYTES;                      // (768,384) bf16
constexpr size_t SZ_KVWT        = (size_t)C2 * C;
constexpr size_t OFF_QWT_BYTE   = OFF_KVWT_BYTE + SZ_KVWT * 2;     // (384,384) bf16
constexpr size_t SZ_QWT         = (size_t)C * C;
constexpr size_t OFF_PROJWT_BYTE= OFF_QWT_BYTE + SZ_QWT * 2;       // (384,384) bf16
constexpr size_t SZ_PROJWT      = (size_t)C * C;
constexpr size_t OFF_FLAG_BYTE  = OFF_PROJWT_BYTE + SZ_PROJWT * 2;
constexpr size_t OFF_XBF_BYTE   = OFF_FLAG_BYTE + 16;              // (B*N,C) bf16
constexpr size_t SZ_XBF         = (size_t)B * N * C;
constexpr size_t WS_BYTES_NEEDED = OFF_XBF_BYTE + SZ_XBF * 2;      // ~52.7 MB

typedef __attribute__((ext_vector_type(8))) short bf16x8;          // MFMA A/B frag
typedef __attribute__((ext_vector_type(8))) unsigned short u16x8;  // raw staging
typedef __attribute__((ext_vector_type(4))) float f32x4;           // MFMA C/D frag

__device__ __forceinline__ unsigned short f2bf_bits(float f) {
    __hip_bfloat16 h = __float2bfloat16(f);
    return *reinterpret_cast<unsigned short*>(&h);
}
__device__ __forceinline__ float bflo(unsigned w) { return __uint_as_float(w << 16); }
__device__ __forceinline__ float bfhi(unsigned w) { return __uint_as_float(w & 0xffff0000u); }

// Flag-dispatched input load: f32=true -> fp32 buffer, else bf16 buffer.
__device__ __forceinline__ float ldin(const void* p, size_t i, bool f32) {
    if (f32) return ((const float*)p)[i];
    return __bfloat162float(((const __hip_bfloat16*)p)[i]);
}

// grid index per reference _grid_idx (fp32, RNE rounding == jnp.round)
__device__ __forceinline__ void grid_idx(float lx, float ly, int& xg, int& yg) {
    float xf = 0.5f * (lx + 1.0f) * (float)Wimg - 0.5f;
    float yf = 0.5f * (ly + 1.0f) * (float)Himg - 0.5f;
    int x = (int)rintf(xf);
    int y = (int)rintf(yf);
    xg = min(max(x, 0), Wimg - 1);
    yg = min(max(y, 0), Himg - 1);
}

// K0: dtype sniffer (fp32 vs bf16 inputs).
__global__ __launch_bounds__(64) void sniff_kernel(const unsigned short* __restrict__ qw_bits,
                                                   int* __restrict__ flag) {
    int t = threadIdx.x;
    int cnt = 0;
    #pragma unroll
    for (int i = 0; i < 8; i++) {
        unsigned u = qw_bits[t * 8 + i];
        float v = __uint_as_float(u << 16);
        if (fabsf(v) > 4.0f) cnt++;
    }
    #pragma unroll
    for (int off = 32; off >= 1; off >>= 1) cnt += __shfl_xor(cnt, off);
    if (t == 0) *flag = (cnt > 8) ? 1 : 0;
}

// Transpose helper: one 32x32 tile of W (K,Nn) -> Wt (Nn,K) bf16 bits.
__device__ __forceinline__ void do_transpose_tile(
    const void* __restrict__ W, unsigned short* __restrict__ Wt,
    int K, int Nn, int n0, int k0, bool f32, int t, float (*tile)[33])
{
    int tx = t & 31, ty = t >> 5;  // 32 x 8
    #pragma unroll
    for (int i = 0; i < 4; i++)
        tile[ty + i * 8][tx] = ldin(W, (size_t)(k0 + ty + i * 8) * Nn + (n0 + tx), f32);
    __syncthreads();
    #pragma unroll
    for (int i = 0; i < 4; i++)
        Wt[(size_t)(n0 + ty + i * 8) * K + (k0 + tx)] = f2bf_bits(tile[tx][ty + i * 8]);
}

// K-prep: fused weight transposes + x->bf16 conversion + accumulator zeroing.
// Job map by blockIdx.x:
//   [0,288)        kvwt transpose  (24 n-tiles x 12 k-tiles)
//   [288,432)      qwt transpose   (12 x 12)
//   [432,576)      projwt transpose(12 x 12)
//   [576,1752)     x -> xbf conversion (1176 blocks x 1024 elems)
//   [1752,2984)    zero ws accumulators (1232 blocks x 4096 floats)
constexpr int PREP_BLOCKS = 2984;
__global__ __launch_bounds__(256) void prep_kernel(
    const void* __restrict__ kv_w, unsigned short* __restrict__ kvwt,
    const void* __restrict__ q_w, unsigned short* __restrict__ qwt,
    const void* __restrict__ proj_w, unsigned short* __restrict__ projwt,
    const void* __restrict__ x, unsigned short* __restrict__ xbf,
    float* __restrict__ zbase, const int* __restrict__ flagp)
{
    __shared__ float tile[32][33];
    const bool f32 = (*flagp != 0);
    const int bid = blockIdx.x, t = threadIdx.x;
    if (bid < 288) {
        int j = bid;
        do_transpose_tile(kv_w, kvwt, C, C2, (j % 24) * 32, (j / 24) * 32, f32, t, tile);
    } else if (bid < 432) {
        int j = bid - 288;
        do_transpose_tile(q_w, qwt, C, C, (j % 12) * 32, (j / 12) * 32, f32, t, tile);
    } else if (bid < 576) {
        int j = bid - 432;
        do_transpose_tile(proj_w, projwt, C, C, (j % 12) * 32, (j / 12) * 32, f32, t, tile);
    } else if (bid < 1752) {
        int i = (bid - 576) * 1024 + t * 4;   // B*N*C = 1,204,224 = 1176*1024 exactly
        #pragma unroll
        for (int j = 0; j < 4; j++)
            xbf[i + j] = f2bf_bits(ldin(x, i + j, f32));
    } else {
        size_t base = (size_t)(bid - 1752) * 4096 + t * 16;
        #pragma unroll
        for (int j = 0; j < 4; j++) {
            size_t i = base + j * 4;
            if (i < ZERO_FLOATS) *(float4*)&zbase[i] = float4{0.f, 0.f, 0.f, 0.f};
        }
    }
}

// K2: fused scatter — token2map (mp/csum/cnt) + pw window-vote, one block per p.
__global__ __launch_bounds__(128) void scatter_kernel(
    const void* __restrict__ loc, const int* __restrict__ idx_agg,
    const void* __restrict__ agg_w,
    const int* __restrict__ idx_agg_src,
    const void* __restrict__ x_source, const void* __restrict__ conf_src,
    float* __restrict__ mp, float* __restrict__ csum, float* __restrict__ cnt,
    float* __restrict__ pw, const int* __restrict__ flagp)
{
    const bool f32 = (*flagp != 0);
    int p = blockIdx.x;
    int b = p / NSRC;
    float lx = ldin(loc, (size_t)p * 2 + 0, f32);
    float ly = ldin(loc, (size_t)p * 2 + 1, f32);
    int xg, yg; grid_idx(lx, ly, xg, yg);
    int pix = yg * Wimg + xg;
    int s = idx_agg_src[p];
    size_t srow = ((size_t)b * N + s) * C;
    float* drow = mp + ((size_t)b * HW + pix) * C;
    for (int c = threadIdx.x; c < C; c += 128)
        atomicAdd(&drow[c], ldin(x_source, srow + c, f32));
    if (threadIdx.x == 0) {
        atomicAdd(&csum[(size_t)b * HW + pix], ldin(conf_src, (size_t)b * N + s, f32));
        atomicAdd(&cnt[(size_t)b * HW + pix], 1.0f);
    } else if (threadIdx.x == 1) {
        int win = (yg / 7) * 8 + (xg / 7);
        int n = idx_agg[p];
        float w = ldin(agg_w, p, f32);
        atomicAdd(&pw[((size_t)b * N + n) * NWIN + win], w);
    }
}

// K3: idx_window = argmax(pw, axis=-1), first-max tiebreak
__global__ __launch_bounds__(256) void argmax_kernel(const float* __restrict__ pw, int* __restrict__ idxw)
{
    int t = blockIdx.x * 256 + threadIdx.x;
    if (t >= B * N) return;
    const float* row = pw + (size_t)t * NWIN;
    float best = row[0]; int bi = 0;
    for (int j = 1; j < NWIN; j++) {
        float v = row[j];
        if (v > best) { best = v; bi = j; }
    }
    idxw[t] = bi;
}

// K6: MFMA GEMM, compile-time A dtype. Optional per-row A scale (rowscale:
// A_eff[m][k] = A[m][k] * 1/(rowscale[m]+1e-6)) — folds token2map normalize.
// Bt: (Nn,K) bf16 bits. c_mode: 0 = fp32 store, 1 = bf16 store, 2 = flag-dtyped.
// Tile 128x128, BK=32, 4 waves each owning 64x64 (4x4 MFMA 16x16x32).
// LDS row stride 40 halfwords: 16B-aligned ds_*_b128, 2-way bank aliasing (free).
template <typename AT>
__global__ __launch_bounds__(256) void mfma_gemm_kernel(
    const AT* __restrict__ A,
    const unsigned short* __restrict__ Bt,
    const void* __restrict__ bias,
    void* __restrict__ Co, int c_mode,
    int M, int Nn, int K, float alpha, const int* __restrict__ flagp,
    const float* __restrict__ rowscale)
{
    constexpr int SA = 40;  // LDS halfword stride per 32-K row
    const bool f32 = (*flagp != 0);
    const bool store_f32 = (c_mode == 0) || (c_mode == 2 && f32);
    __shared__ unsigned short As[128 * SA];
    __shared__ unsigned short Bs[128 * SA];
    const int t = threadIdx.x;
    const int wave = t >> 6, lane = t & 63;
    const int quad = lane >> 4, l16 = lane & 15;
    const int wm = (wave >> 1) * 64, wn = (wave & 1) * 64;
    const int bm = blockIdx.y * 128, bn = blockIdx.x * 128;

    f32x4 acc[4][4] = {};

    for (int k0 = 0; k0 < K; k0 += 32) {
        #pragma unroll
        for (int ss = 0; ss < 2; ss++) {
            int s = t + ss * 256;
            int row = s >> 2, ch = s & 3;
            int grow = bm + row; if (grow >= M) grow = M - 1;
            if constexpr (std::is_same<AT, float>::value) {
                const float* ga = A + (size_t)grow * K + k0 + ch * 8;
                float sc = rowscale ? (1.0f / (rowscale[grow] + 1e-6f)) : 1.0f;
                float4 v0 = *(const float4*)ga;
                float4 v1 = *(const float4*)(ga + 4);
                u16x8 av;
                av[0] = f2bf_bits(v0.x * sc); av[1] = f2bf_bits(v0.y * sc);
                av[2] = f2bf_bits(v0.z * sc); av[3] = f2bf_bits(v0.w * sc);
                av[4] = f2bf_bits(v1.x * sc); av[5] = f2bf_bits(v1.y * sc);
                av[6] = f2bf_bits(v1.z * sc); av[7] = f2bf_bits(v1.w * sc);
                *(u16x8*)&As[row * SA + ch * 8] = av;
            } else {
                *(u16x8*)&As[row * SA + ch * 8] =
                    *(const u16x8*)(A + (size_t)grow * K + k0 + ch * 8);
            }
            *(u16x8*)&Bs[row * SA + ch * 8] =
                *(const u16x8*)(Bt + (size_t)(bn + row) * K + k0 + ch * 8);
        }
        __syncthreads();

        bf16x8 af[4], bf[4];
        #pragma unroll
        for (int i = 0; i < 4; i++) {
            af[i] = *(const bf16x8*)&As[(wm + i * 16 + l16) * SA + quad * 8];
            bf[i] = *(const bf16x8*)&Bs[(wn + i * 16 + l16) * SA + quad * 8];
        }
        #pragma unroll
        for (int i = 0; i < 4; i++)
            #pragma unroll
            for (int j = 0; j < 4; j++)
                acc[i][j] = __builtin_amdgcn_mfma_f32_16x16x32_bf16(af[i], bf[j], acc[i][j], 0, 0, 0);
        __syncthreads();
    }

    // epilogue: C/D layout col=lane&15, row=quad*4+reg
    #pragma unroll
    for (int i = 0; i < 4; i++) {
        int growb = bm + wm + i * 16 + quad * 4;
        #pragma unroll
        for (int j = 0; j < 4; j++) {
            int gcol = bn + wn + j * 16 + l16;
            float bv = ldin(bias, gcol, f32);
            #pragma unroll
            for (int r = 0; r < 4; r++) {
                int grow = growb + r;
                if (grow < M) {
                    float v = (acc[i][j][r] + bv) * alpha;
                    size_t idx = (size_t)grow * Nn + gcol;
                    if (store_f32) ((float*)Co)[idx] = v;
                    else           ((unsigned short*)Co)[idx] = f2bf_bits(v);
                }
            }
        }
    }
}

// K7: window-centric attention v4b — head-split blocks; conf computed on the fly.
// Grid: B*NWIN*4; block handles head pair par = blk&3 (heads 2par, 2par+1).
// 512 threads = 8 waves; wave = (quarter, head'). Loop-invariant register
// fragments (k-row, v-col); q via wave-uniform scalar loads; PV via p-store +
// broadcast float4 reads. __launch_bounds__(512,4) keeps fragments in registers.
__global__ __launch_bounds__(512, 4) void attn_win_kernel(
    const float* __restrict__ q,              // (B*N, C) pre-scaled
    const unsigned short* __restrict__ kv,    // (B*HW, 768 halfwords): [k | v]
    const float* __restrict__ csum,           // (B*HW)
    const float* __restrict__ cntb,           // (B*HW)
    const int* __restrict__ idxw,             // (B*N)
    unsigned short* __restrict__ attno)       // (B*N, C) bf16 bits
{
    constexpr int SK  = 104;  // k row stride (u16)
    constexpr int SVT = 58;   // vt row stride (u16)
    constexpr int CH  = 2 * D;   // 96 channels per block (2 heads)
    __shared__ unsigned short s_k[KWIN * SK];    // 10,192 B  [key][c']
    __shared__ unsigned short s_vt[CH * SVT];    // 11,136 B  [c'][key]
    __shared__ float s_p[8][KPAD];               //  1,792 B
    __shared__ unsigned short s_list[N];         //  1,568 B
    __shared__ float s_conf[KWIN];
    __shared__ int   s_cnt;

    const int t   = threadIdx.x;
    const int blk = blockIdx.x;                 // b*256 + win*4 + par
    const int b   = blk >> 8;
    const int win = (blk >> 2) & 63;
    const int par = blk & 3;
    const int wy = win >> 3, wx = win & 7;

    if (t == 0) s_cnt = 0;
    __syncthreads();
    for (int n = t; n < N; n += 512) {
        if (idxw[b * N + n] == win) {
            int slot = atomicAdd(&s_cnt, 1);
            s_list[slot] = (unsigned short)n;
        }
    }
    const unsigned* kvw = (const unsigned*)kv;
    for (int idx = t; idx < KWIN * (CH / 2); idx += 512) {
        int row = idx / (CH / 2), cw = idx % (CH / 2);
        int pix = (wy * 7 + row / 7) * Wimg + wx * 7 + row % 7;
        size_t gbase = ((size_t)b * HW + pix) * 384 + par * (CH / 2);
        *(unsigned*)&s_k[row * SK + cw * 2] = kvw[gbase + cw];
        unsigned vv = kvw[gbase + 192 + cw];
        int c0 = cw * 2;
        s_vt[(c0 + 0) * SVT + row] = (unsigned short)(vv & 0xffffu);
        s_vt[(c0 + 1) * SVT + row] = (unsigned short)(vv >> 16);
    }
    if (t < CH) {
        #pragma unroll
        for (int j = KWIN; j < KPAD; j++) s_vt[t * SVT + j] = 0;
    }
    if (t < KWIN) {
        int pix = (wy * 7 + t / 7) * Wimg + wx * 7 + t % 7;
        float iv = 1.0f / (cntb[(size_t)b * HW + pix] + 1e-6f);
        s_conf[t] = csum[(size_t)b * HW + pix] * iv;
    }
    __syncthreads();

    const int cnt   = s_cnt;
    const int wave  = t >> 6;
    const int lane  = t & 63;
    const int hloc  = __builtin_amdgcn_readfirstlane(wave & 1);
    const int quart = wave >> 1;
    const int h     = par * 2 + hloc;

    if (lane >= KWIN && lane < KPAD) s_p[wave][lane] = 0.0f;

    const int krow = (lane < KWIN) ? lane : 0;
    uint4 kf[3];
    #pragma unroll
    for (int j = 0; j < 3; j++)
        kf[j] = *(const uint4*)&s_k[krow * SK + hloc * D + j * 16];
    const int dl = (lane < D) ? lane : 0;
    unsigned vw[28];
    {
        const unsigned short* vrow = &s_vt[(hloc * D + dl) * SVT];
        #pragma unroll
        for (int j = 0; j < 28; j++) vw[j] = *(const unsigned*)&vrow[j * 2];
    }
    const float confk = (lane < KWIN) ? s_conf[lane] : 0.0f;

    for (int ti = quart; ti < cnt; ti += 4) {
        const int n0 = __builtin_amdgcn_readfirstlane((int)s_list[ti]);
        const size_t bn = (size_t)b * N + n0;
        const float* qrow = q + bn * C + h * D;   // wave-uniform -> scalar loads

        float l = -INFINITY;
        if (lane < KWIN) {
            float acc = confk;
            #pragma unroll
            for (int j = 0; j < 3; j++) {
                const int c = j * 16;
                acc += qrow[c +  0] * bflo(kf[j].x) + qrow[c +  1] * bfhi(kf[j].x);
                acc += qrow[c +  2] * bflo(kf[j].y) + qrow[c +  3] * bfhi(kf[j].y);
                acc += qrow[c +  4] * bflo(kf[j].z) + qrow[c +  5] * bfhi(kf[j].z);
                acc += qrow[c +  6] * bflo(kf[j].w) + qrow[c +  7] * bfhi(kf[j].w);
                uint4 k2 = *(const uint4*)&s_k[krow * SK + hloc * D + j * 16 + 8];
                acc += qrow[c +  8] * bflo(k2.x) + qrow[c +  9] * bfhi(k2.x);
                acc += qrow[c + 10] * bflo(k2.y) + qrow[c + 11] * bfhi(k2.y);
                acc += qrow[c + 12] * bflo(k2.z) + qrow[c + 13] * bfhi(k2.z);
                acc += qrow[c + 14] * bflo(k2.w) + qrow[c + 15] * bfhi(k2.w);
            }
            l = acc;
        }
        float m = l;
        #pragma unroll
        for (int off = 32; off >= 1; off >>= 1) m = fmaxf(m, __shfl_xor(m, off));
        float e = (lane < KWIN) ? expf(l - m) : 0.0f;
        float ssum = e;
        #pragma unroll
        for (int off = 32; off >= 1; off >>= 1) ssum += __shfl_xor(ssum, off);
        if (lane < KWIN) s_p[wave][lane] = e / ssum;
        __builtin_amdgcn_wave_barrier();

        float acc = 0.0f;
        const float4* pv4 = (const float4*)&s_p[wave][0];
        #pragma unroll
        for (int j = 0; j < KPAD / 4; j++) {
            float4 p4 = pv4[j];
            unsigned w0 = vw[j * 2], w1 = vw[j * 2 + 1];
            acc += p4.x * bflo(w0) + p4.y * bfhi(w0);
            acc += p4.z * bflo(w1) + p4.w * bfhi(w1);
        }
        if (lane < D) attno[bn * C + h * D + lane] = f2bf_bits(acc);
    }
}

extern "C" void kernel_launch(void* const* d_in, const int* in_sizes, int n_in,
                              void* d_out, int out_size, void* d_ws, size_t ws_size,
                              hipStream_t stream) {
    if (ws_size < WS_BYTES_NEEDED) return;  // visible failure if ws too small

    const void* x        = d_in[0];
    const void* loc      = d_in[1];
    const int*  idx_agg  = (const int*)d_in[2];
    const void* agg_w    = d_in[3];
    const void* x_source = d_in[4];
    const int*  idx_asrc = (const int*)d_in[5];
    const void* conf_src = d_in[6];
    int wb = 9;
    if (!(n_in >= 15 && in_sizes[7] == 1 && in_sizes[8] == 1)) wb = 7;
    const void* q_w    = d_in[wb + 0];
    const void* q_b    = d_in[wb + 1];
    const void* kv_w   = d_in[wb + 2];
    const void* kv_b   = d_in[wb + 3];
    const void* proj_w = d_in[wb + 4];
    const void* proj_b = d_in[wb + 5];

    float* ws   = (float*)d_ws;
    float* pw   = ws + OFF_PW;
    float* mp   = ws + OFF_MP;
    float* csum = ws + OFF_CSUM;
    float* cnt  = ws + OFF_CNT;
    float* q    = ws + OFF_Q;
    int*   idxw = (int*)(ws + OFF_IDXW);
    unsigned short* attno = (unsigned short*)(ws + OFF_ATTNO);
    unsigned short* kv = (unsigned short*)(ws + OFF_KV_F);
    unsigned short* kvwt   = (unsigned short*)((char*)d_ws + OFF_KVWT_BYTE);
    unsigned short* qwt    = (unsigned short*)((char*)d_ws + OFF_QWT_BYTE);
    unsigned short* projwt = (unsigned short*)((char*)d_ws + OFF_PROJWT_BYTE);
    int* flag = (int*)((char*)d_ws + OFF_FLAG_BYTE);
    unsigned short* xbf = (unsigned short*)((char*)d_ws + OFF_XBF_BYTE);

    // 1) dtype sniff
    sniff_kernel<<<1, 64, 0, stream>>>((const unsigned short*)q_w, flag);
    // 2) fused prep: weight transposes + x->bf16 + zero accumulators
    prep_kernel<<<PREP_BLOCKS, 256, 0, stream>>>(
        kv_w, kvwt, q_w, qwt, proj_w, projwt, x, xbf, ws, flag);
    // 3) fused scatter: token2map + pw vote
    scatter_kernel<<<B * NSRC, 128, 0, stream>>>(
        loc, idx_agg, agg_w, idx_asrc, x_source, conf_src, mp, csum, cnt, pw, flag);
    // 4) argmax -> idx_window
    argmax_kernel<<<(B * N + 255) / 256, 256, 0, stream>>>(pw, idxw);

    const float scale = (float)(1.0 / sqrt((double)D));
    // 5) q = (x @ q_w + q_b) * scale   [MFMA, bf16 A, fp32 out]
    mfma_gemm_kernel<unsigned short><<<dim3(C / 128, (B * N + 127) / 128), 256, 0, stream>>>(
        xbf, qwt, q_b, q, 0, B * N, C, C, scale, flag, nullptr);
    // 6) kv = (mp * 1/(cnt+eps)) @ kv_w + kv_b  [MFMA, fp32 A + row scale, bf16 out]
    mfma_gemm_kernel<float><<<dim3(C2 / 128, (B * HW) / 128), 256, 0, stream>>>(
        mp, kvwt, kv_b, kv, 1, B * HW, C2, C, 1.0f, flag, cnt);
    // 7) attention (window-centric v4b, conf on the fly)
    attn_win_kernel<<<B * NWIN * 4, 512, 0, stream>>>(q, kv, csum, cnt, idxw, attno);
    // 8) out = attno @ proj_w + proj_b [MFMA, bf16 A, flag-dtyped out]
    mfma_gemm_kernel<unsigned short><<<dim3(C / 128, (B * N + 127) / 128), 256, 0, stream>>>(
        attno, projwt, proj_b, d_out, 2, B * N, C, C, 1.0f, flag, nullptr);

    (void)out_size;
}